// Round 16
// baseline (1417.734 us; speedup 1.0000x reference)
//
#include <hip/hip_runtime.h>

// Problem constants (from reference setup_inputs)
#define NVOX   4096   // B voxels
#define NMEAS  256    // M measurements
#define NATOMS 512    // K atoms
#define NITER  30

typedef __attribute__((ext_vector_type(8))) short s8v;   // 8 bf16 (4 VGPR) MFMA frag
typedef __attribute__((ext_vector_type(4))) short s4v;
typedef __attribute__((ext_vector_type(4))) float f32x4;

// bf16 round-to-nearest-even split helpers (no NaN/Inf in this problem)
__device__ __forceinline__ unsigned short f2bf(float x) {
    unsigned u = __builtin_bit_cast(unsigned, x);
    u += 0x7fff + ((u >> 16) & 1);
    return (unsigned short)(u >> 16);
}
__device__ __forceinline__ float bf2f(unsigned short b) {
    unsigned u = ((unsigned)b) << 16;
    return __builtin_bit_cast(float, u);
}
// g(v) = (z - u) collapsed through v = x + u :  relu(v-0.1) - min(v,0.1)
__device__ __forceinline__ float g_of(float v) {
    return fmaxf(v - 0.1f, 0.0f) - fminf(v, 0.1f);
}

// ---------------------------------------------------------------------------
// K0: G = I + A*A^T in fp64 (Gd) + fp32 copy (Gf) for the sweep
// ---------------------------------------------------------------------------
__global__ __launch_bounds__(256) void g_kernel_d(const float* __restrict__ A,
                                                  double* __restrict__ Gd,
                                                  float* __restrict__ Gf) {
    __shared__ float arow[NATOMS];
    int i = blockIdx.x;
    for (int k = threadIdx.x; k < NATOMS; k += 256) arow[k] = A[i * NATOMS + k];
    __syncthreads();
    int j = threadIdx.x;
    const float* aj = A + j * NATOMS;
    double s = (i == j) ? 1.0 : 0.0;
#pragma unroll 4
    for (int k = 0; k < NATOMS; ++k) s += (double)arow[k] * (double)aj[k];
    Gd[i * NMEAS + j] = s;
    Gf[i * NMEAS + j] = (float)s;
}

// ---------------------------------------------------------------------------
// K1: SPD inverse of Gf (256x256) via scalar symmetric SWEEP — r5-proven,
// 283us structural floor (r6/r7/r9/r14 blocked variants all spilled).
// sweep(all) = -G^{-1}; negate on store.
// ---------------------------------------------------------------------------
__global__ __launch_bounds__(1024) void sweep_inverse(const float* __restrict__ src,
                                                      float* __restrict__ dst) {
    __shared__ float s_dn[NMEAS];
    __shared__ float s_dt[NMEAS];
    int t = threadIdx.x;
    int rb = t & 31;
    int cb = t >> 5;
    float vals[8][8];
#pragma unroll
    for (int i = 0; i < 8; ++i) {
        const float* row = &src[(8 * rb + i) * NMEAS + 8 * cb];
        float4 a = *(const float4*)row;
        float4 b = *(const float4*)(row + 4);
        vals[i][0] = a.x; vals[i][1] = a.y; vals[i][2] = a.z; vals[i][3] = a.w;
        vals[i][4] = b.x; vals[i][5] = b.y; vals[i][6] = b.z; vals[i][7] = b.w;
    }
#pragma unroll 1
    for (int p = 0; p < NMEAS; ++p) {
        int pb = p >> 3, pi = p & 7;
        __syncthreads();
        if (cb == pb) {
#pragma unroll
            for (int i = 0; i < 8; ++i) {
                float v = vals[i][0];
#pragma unroll
                for (int j = 1; j < 8; ++j) if (pi == j) v = vals[i][j];
                s_dn[8 * rb + i] = v;
                s_dt[i * 32 + rb] = v;
            }
        }
        __syncthreads();
        float d   = s_dn[p];
        float inv = 1.0f / d;
        float rv[8], cv[8];
#pragma unroll
        for (int i = 0; i < 8; ++i) rv[i] = s_dt[i * 32 + rb];
#pragma unroll
        for (int j = 0; j < 8; ++j) cv[j] = s_dn[8 * cb + j] * inv;
#pragma unroll
        for (int i = 0; i < 8; ++i)
#pragma unroll
            for (int j = 0; j < 8; ++j) vals[i][j] -= rv[i] * cv[j];
        if (rb == pb) {
#pragma unroll
            for (int i = 0; i < 8; ++i) if (pi == i) {
#pragma unroll
                for (int j = 0; j < 8; ++j) vals[i][j] = cv[j];
            }
        }
        if (cb == pb) {
#pragma unroll
            for (int j = 0; j < 8; ++j) if (pi == j) {
#pragma unroll
                for (int i = 0; i < 8; ++i)
                    vals[i][j] = (rb == pb && pi == i) ? -inv : rv[i] * inv;
            }
        }
    }
#pragma unroll
    for (int i = 0; i < 8; ++i)
#pragma unroll
        for (int j = 0; j < 8; ++j)
            dst[(8 * rb + i) * NMEAS + 8 * cb + j] = -vals[i][j];
}

// ---------------------------------------------------------------------------
// fp64 Newton refinement:  P = Gd @ X ;  Xn = 2X - X @ P   (X input fp32/fp64)
// ---------------------------------------------------------------------------
template <typename TB>
__global__ __launch_bounds__(256) void mm_gd(const double* __restrict__ Gd,
                                             const TB* __restrict__ X,
                                             double* __restrict__ P) {
    __shared__ __align__(16) double row[NMEAS];
    int i = blockIdx.x;
    row[threadIdx.x] = Gd[i * NMEAS + threadIdx.x];
    __syncthreads();
    int j = threadIdx.x;
    double s = 0.0;
#pragma unroll 4
    for (int k = 0; k < NMEAS; ++k) s += row[k] * (double)X[k * NMEAS + j];
    P[i * NMEAS + j] = s;
}

template <typename TB>
__global__ __launch_bounds__(256) void upd_newton(const TB* __restrict__ X,
                                                  const double* __restrict__ P,
                                                  double* __restrict__ Xn) {
    __shared__ __align__(16) double row[NMEAS];
    int i = blockIdx.x;
    row[threadIdx.x] = (double)X[i * NMEAS + threadIdx.x];
    __syncthreads();
    int j = threadIdx.x;
    double s = 0.0;
#pragma unroll 4
    for (int k = 0; k < NMEAS; ++k) s += row[k] * P[k * NMEAS + j];
    Xn[i * NMEAS + j] = 2.0 * row[j] - s;
}

// ---------------------------------------------------------------------------
// K2: Hd = X2d @ A   (fp64 [256][256] @ fp32 [256][512] -> fp64 [256][512])
// ---------------------------------------------------------------------------
__global__ __launch_bounds__(256) void h_kernel_d(const double* __restrict__ Gi,
                                                  const float* __restrict__ A,
                                                  double* __restrict__ H) {
    __shared__ __align__(16) double grow[NMEAS];
    int i = blockIdx.x;
    grow[threadIdx.x] = Gi[i * NMEAS + threadIdx.x];
    __syncthreads();
    int k0 = threadIdx.x;
    double s0 = 0.0, s1 = 0.0;
#pragma unroll 4
    for (int j = 0; j < NMEAS; ++j) {
        double g = grow[j];
        s0 += g * (double)A[j * NATOMS + k0];
        s1 += g * (double)A[j * NATOMS + k0 + 256];
    }
    H[i * NATOMS + k0] = s0;
    H[i * NATOMS + k0 + 256] = s1;
}

// ---------------------------------------------------------------------------
// K3: W = I - A^T @ Hd  (fp64 accumulate), stored as bf16 hi/lo split
// ---------------------------------------------------------------------------
__global__ __launch_bounds__(256) void w_kernel_d(const float* __restrict__ A,
                                                  const double* __restrict__ H,
                                                  unsigned short* __restrict__ Whg,
                                                  unsigned short* __restrict__ Wlg) {
    __shared__ __align__(16) double acol[NMEAS];
    int p = blockIdx.x;
    acol[threadIdx.x] = (double)A[threadIdx.x * NATOMS + p];
    __syncthreads();
    int q0 = threadIdx.x;
    double s0 = 0.0, s1 = 0.0;
#pragma unroll 4
    for (int m = 0; m < NMEAS; ++m) {
        double a = acol[m];
        s0 += a * H[m * NATOMS + q0];
        s1 += a * H[m * NATOMS + q0 + 256];
    }
    double w0 = ((p == q0)       ? 1.0 : 0.0) - s0;
    double w1 = ((p == q0 + 256) ? 1.0 : 0.0) - s1;
    unsigned short h0 = f2bf((float)w0), h1 = f2bf((float)w1);
    Whg[p * NATOMS + q0]       = h0;
    Wlg[p * NATOMS + q0]       = f2bf((float)(w0 - (double)bf2f(h0)));
    Whg[p * NATOMS + q0 + 256] = h1;
    Wlg[p * NATOMS + q0 + 256] = f2bf((float)(w1 - (double)bf2f(h1)));
}

// ---------------------------------------------------------------------------
// K4: Delta0 = AtY (= t_1, since t_0 = 0), stored split bf16 hi/lo,
//     TRANSPOSED to [4096 voxels][512 atoms].
// AtY[k][b] = sum_m A[m][k] * Y[b][m]
// ---------------------------------------------------------------------------
__global__ __launch_bounds__(256) void aty_kernel(const float* __restrict__ A,
                                                  const float* __restrict__ Y,
                                                  unsigned short* __restrict__ Dh0,
                                                  unsigned short* __restrict__ Dl0) {
    __shared__ __align__(16) float At[64][65];
    __shared__ __align__(16) float Yt[64][65];
    int b0 = blockIdx.x * 64, k0 = blockIdx.y * 64;
    int t = threadIdx.x, tx = t & 15, ty = t >> 4;
    float acc[4][4] = {};
    for (int m0 = 0; m0 < NMEAS; m0 += 64) {
        __syncthreads();
        {
            int kk = t & 63, mr = t >> 6;
#pragma unroll
            for (int p = 0; p < 16; ++p)
                At[mr + 4 * p][kk] = A[(m0 + mr + 4 * p) * NATOMS + k0 + kk];
            int mm = t & 63, br = t >> 6;
#pragma unroll
            for (int p = 0; p < 16; ++p)
                Yt[mm][br + 4 * p] = Y[(b0 + br + 4 * p) * NMEAS + m0 + mm];
        }
        __syncthreads();
#pragma unroll 4
        for (int m = 0; m < 64; ++m) {
            float av[4], yv[4];
#pragma unroll
            for (int i = 0; i < 4; ++i) av[i] = At[m][ty * 4 + i];
#pragma unroll
            for (int j = 0; j < 4; ++j) yv[j] = Yt[m][tx * 4 + j];
#pragma unroll
            for (int i = 0; i < 4; ++i)
#pragma unroll
                for (int j = 0; j < 4; ++j) acc[i][j] += av[i] * yv[j];
        }
    }
#pragma unroll
    for (int j = 0; j < 4; ++j) {
        int b = b0 + tx * 4 + j;
        s4v h4, l4;
#pragma unroll
        for (int i = 0; i < 4; ++i) {
            float f = acc[i][j];
            unsigned short h = f2bf(f);
            h4[i] = (short)h;
            l4[i] = (short)f2bf(f - bf2f(h));
        }
        *(s4v*)&Dh0[(long)b * NATOMS + k0 + ty * 4] = h4;
        *(s4v*)&Dl0[(long)b * NATOMS + k0 + ty * 4] = l4;
    }
}

// ---------------------------------------------------------------------------
// K5: PERSISTENT fused ADMM v2 — all 30 iterations, one launch.
// r12/r13 failed because 512-thr blocks were allocator-capped at 64 VGPR
// while persistent state alone was 64 (xacc+vreg) -> acc spilled. v2 fixes
// the STATE BUDGET: 256-thr block (the only shape seen getting >128 regs),
// v moved to LDS -> persistent regs = acc[8] only (32). Peak live set
// ~60 regs — fits even a worst-case 64-reg grant.
// Block owns 16 voxels (grid 256 = 1/CU). Per iter:
//   acc (=x) += 3-term split GEMM over W (global, L2-resident broadcast)
//              x Delta (LDS, CHUNK-MAJOR: unit (kc*16+vox)*4+kg -> a wave's
//              B-read is 64 lanes x 16B CONTIGUOUS = conflict-free)
//   epilogue: v' = x + min(v,0.1) (v in LDS); Delta' = g(v')-g(v) -> LDS
// 2 barriers/iter. C-in accumulation numerics already validated by r12/r13
// (absmax 0.00390625). LDS: Dh 16KB + Dl 16KB + v 33KB = 65KB.
// ---------------------------------------------------------------------------
__global__ __launch_bounds__(256) void admm_fused2(
        const unsigned short* __restrict__ Whg,
        const unsigned short* __restrict__ Wlg,
        const unsigned short* __restrict__ D0h,
        const unsigned short* __restrict__ D0l,
        float* __restrict__ out) {
    __shared__ __align__(16) unsigned short DhL[8192];  // chunk-major, 16KB
    __shared__ __align__(16) unsigned short DlL[8192];
    __shared__ __align__(16) float vL[16 * 516];        // [vox][atom] pitch 516

    const int t = threadIdx.x;
    const int lane = t & 63, wv = t >> 6;   // 4 waves
    const int ln = lane & 15, kg = lane >> 4;
    const long vb = (long)blockIdx.x * 16;  // this block's voxel base

    // ---- preload Delta_0 (global linear [vox][atom] -> chunk-major LDS)
#pragma unroll
    for (int q = 0; q < 4; ++q) {
        int u = q * 256 + t;                // 1024 s8v units per buffer
        int vox = u >> 6, a8 = u & 63;      // atom group a = a8*8
        int ldsU = ((a8 >> 2) * 16 + vox) * 4 + (a8 & 3);
        long g = (vb + vox) * NATOMS + a8 * 8;
        *(s8v*)&DhL[ldsU * 8] = *(const s8v*)&D0h[g];
        *(s8v*)&DlL[ldsU * 8] = *(const s8v*)&D0l[g];
    }
    for (int i = t; i < 16 * 516; i += 256) vL[i] = 0.0f;   // v0 = 0
    __syncthreads();

    f32x4 acc[8] = {};                      // x = MFMA accumulator (32 VGPR)

#pragma unroll 1
    for (int it = 0; it < NITER; ++it) {
        // ---- GEMM: acc += W @ Delta  (C-in = x_{k-1})
#pragma unroll 1
        for (int kc = 0; kc < 16; ++kc) {
            const int bidx = (((kc * 16 + ln) * 4) + kg) * 8;
            s8v bh = *(const s8v*)&DhL[bidx];
            s8v bl = *(const s8v*)&DlL[bidx];
            const int ko = kc * 32 + kg * 8;
#pragma unroll
            for (int mt = 0; mt < 8; ++mt) {
                const long row = (long)((wv * 8 + mt) * 16 + ln) * NATOMS + ko;
                s8v ah = *(const s8v*)&Whg[row];
                s8v al = *(const s8v*)&Wlg[row];
                acc[mt] = __builtin_amdgcn_mfma_f32_16x16x32_bf16(ah, bh, acc[mt], 0, 0, 0);
                acc[mt] = __builtin_amdgcn_mfma_f32_16x16x32_bf16(ah, bl, acc[mt], 0, 0, 0);
                acc[mt] = __builtin_amdgcn_mfma_f32_16x16x32_bf16(al, bh, acc[mt], 0, 0, 0);
            }
        }
        if (it == NITER - 1) break;         // acc holds x_30
        __syncthreads();                    // all waves done reading Delta
        // ---- epilogue: v' = x + min(v,0.1); Delta' = g(v')-g(v) -> LDS
#pragma unroll
        for (int mt = 0; mt < 8; ++mt) {
            int a0 = (wv * 8 + mt) * 16 + kg * 4;   // 4 consecutive atoms
            float* vp = &vL[ln * 516 + a0];
            f32x4 vo = *(const f32x4*)vp;
            f32x4 vn;
            s4v h4, l4;
#pragma unroll
            for (int j = 0; j < 4; ++j) {
                float x = acc[mt][j];
                float vnj = x + fminf(vo[j], 0.1f);
                float dlt = g_of(vnj) - g_of(vo[j]);
                vn[j] = vnj;
                unsigned short h = f2bf(dlt);
                h4[j] = (short)h;
                l4[j] = (short)f2bf(dlt - bf2f(h));
            }
            *(f32x4*)vp = vn;
            // chunk-major Delta store: a -> ((a>>5)*16+vox)*32 + ((a>>3)&3)*8 + (a&7)
            int lin = ((a0 >> 5) * 16 + ln) * 32 + ((a0 >> 3) & 3) * 8 + (a0 & 7);
            *(s4v*)&DhL[lin] = h4;
            *(s4v*)&DlL[lin] = l4;
        }
        __syncthreads();                    // Delta ready for next GEMM
    }
    // ---- final: out[vox][atom] = x_30 (float4 direct)
#pragma unroll
    for (int mt = 0; mt < 8; ++mt) {
        int a0 = (wv * 8 + mt) * 16 + kg * 4;
        *(f32x4*)&out[(vb + ln) * NATOMS + a0] = acc[mt];
    }
}

// ---------------------------------------------------------------------------
extern "C" void kernel_launch(void* const* d_in, const int* in_sizes, int n_in,
                              void* d_out, int out_size, void* d_ws, size_t ws_size,
                              hipStream_t stream) {
    const float* Y = (const float*)d_in[0];   // [4096][256]
    const float* A = (const float*)d_in[1];   // [256][512]

    // ws layout (float units), lifetime-checked overlays (r3-r15 footprint).
    float* ws = (float*)d_ws;
    double* Gd  = (double*)(ws + 0);        // [0,131072)       dead after step 5
    float*  Gf  = ws + 131072;              // [131072,196608)  dead after sweep
    float*  X0f = ws + 196608;              // [196608,262144)  dead after step 4
    double* X1d = (double*)(ws + 262144);   // [262144,393216)  dead after step 6
    double* Pd  = (double*)(ws + 393216);   // [393216,524288)  dead after step 6
    double* X2d = (double*)(ws + 131072);   // overlays Gf+X0f (both dead)
    double* Hd  = (double*)(ws + 393216);   // [393216,655360) overlays Pd (dead)
    unsigned short* Whg = (unsigned short*)(ws + 0);        // overlays Gd (dead)
    unsigned short* Wlg = (unsigned short*)(ws + 131072);   // overlays X2d (dead after h)
    unsigned short* DAh = (unsigned short*)(ws + 2752512);  // Delta_0 hi
    unsigned short* DAl = (unsigned short*)(ws + 3801088);  // Delta_0 lo
    float* outp = (float*)d_out;

    g_kernel_d<<<256, 256, 0, stream>>>(A, Gd, Gf);                 // 1
    sweep_inverse<<<1, 1024, 0, stream>>>(Gf, X0f);                 // 2
    mm_gd<float><<<256, 256, 0, stream>>>(Gd, X0f, Pd);             // 3
    upd_newton<float><<<256, 256, 0, stream>>>(X0f, Pd, X1d);       // 4
    mm_gd<double><<<256, 256, 0, stream>>>(Gd, X1d, Pd);            // 5
    upd_newton<double><<<256, 256, 0, stream>>>(X1d, Pd, X2d);      // 6
    h_kernel_d<<<256, 256, 0, stream>>>(X2d, A, Hd);                // 7
    w_kernel_d<<<512, 256, 0, stream>>>(A, Hd, Whg, Wlg);           // 8
    aty_kernel<<<dim3(64, 8), 256, 0, stream>>>(A, Y, DAh, DAl);    // 9

    // 10: all 30 ADMM iterations, one persistent launch (256 blocks x 16 vox)
    admm_fused2<<<256, 256, 0, stream>>>(Whg, Wlg, DAh, DAl, outp);
}

// Round 17
// 1347.402 us; speedup vs baseline: 1.0522x; 1.0522x over previous
//
#include <hip/hip_runtime.h>

// Problem constants (from reference setup_inputs)
#define NVOX   4096   // B voxels
#define NMEAS  256    // M measurements
#define NATOMS 512    // K atoms
#define NITER  30

typedef __attribute__((ext_vector_type(8))) short s8v;   // 8 bf16 (4 VGPR) MFMA frag
typedef __attribute__((ext_vector_type(4))) short s4v;
typedef __attribute__((ext_vector_type(4))) float f32x4;

// bf16 round-to-nearest-even split helpers (no NaN/Inf in this problem)
__device__ __forceinline__ unsigned short f2bf(float x) {
    unsigned u = __builtin_bit_cast(unsigned, x);
    u += 0x7fff + ((u >> 16) & 1);
    return (unsigned short)(u >> 16);
}
__device__ __forceinline__ float bf2f(unsigned short b) {
    unsigned u = ((unsigned)b) << 16;
    return __builtin_bit_cast(float, u);
}
// g(v) = (z - u) collapsed through v = x + u :  relu(v-0.1) - min(v,0.1)
__device__ __forceinline__ float g_of(float v) {
    return fmaxf(v - 0.1f, 0.0f) - fminf(v, 0.1f);
}

// ---------------------------------------------------------------------------
// K0: G = I + A*A^T in fp64 (Gd) + fp32 copy (Gf) for the sweep
// ---------------------------------------------------------------------------
__global__ __launch_bounds__(256) void g_kernel_d(const float* __restrict__ A,
                                                  double* __restrict__ Gd,
                                                  float* __restrict__ Gf) {
    __shared__ float arow[NATOMS];
    int i = blockIdx.x;
    for (int k = threadIdx.x; k < NATOMS; k += 256) arow[k] = A[i * NATOMS + k];
    __syncthreads();
    int j = threadIdx.x;
    const float* aj = A + j * NATOMS;
    double s = (i == j) ? 1.0 : 0.0;
#pragma unroll 4
    for (int k = 0; k < NATOMS; ++k) s += (double)arow[k] * (double)aj[k];
    Gd[i * NMEAS + j] = s;
    Gf[i * NMEAS + j] = (float)s;
}

// ---------------------------------------------------------------------------
// K1: SPD inverse of Gf (256x256) via scalar symmetric SWEEP — r5-proven,
// 283us structural floor (r6/r7/r9/r14 blocked variants all spilled).
// sweep(all) = -G^{-1}; negate on store.
// ---------------------------------------------------------------------------
__global__ __launch_bounds__(1024) void sweep_inverse(const float* __restrict__ src,
                                                      float* __restrict__ dst) {
    __shared__ float s_dn[NMEAS];
    __shared__ float s_dt[NMEAS];
    int t = threadIdx.x;
    int rb = t & 31;
    int cb = t >> 5;
    float vals[8][8];
#pragma unroll
    for (int i = 0; i < 8; ++i) {
        const float* row = &src[(8 * rb + i) * NMEAS + 8 * cb];
        float4 a = *(const float4*)row;
        float4 b = *(const float4*)(row + 4);
        vals[i][0] = a.x; vals[i][1] = a.y; vals[i][2] = a.z; vals[i][3] = a.w;
        vals[i][4] = b.x; vals[i][5] = b.y; vals[i][6] = b.z; vals[i][7] = b.w;
    }
#pragma unroll 1
    for (int p = 0; p < NMEAS; ++p) {
        int pb = p >> 3, pi = p & 7;
        __syncthreads();
        if (cb == pb) {
#pragma unroll
            for (int i = 0; i < 8; ++i) {
                float v = vals[i][0];
#pragma unroll
                for (int j = 1; j < 8; ++j) if (pi == j) v = vals[i][j];
                s_dn[8 * rb + i] = v;
                s_dt[i * 32 + rb] = v;
            }
        }
        __syncthreads();
        float d   = s_dn[p];
        float inv = 1.0f / d;
        float rv[8], cv[8];
#pragma unroll
        for (int i = 0; i < 8; ++i) rv[i] = s_dt[i * 32 + rb];
#pragma unroll
        for (int j = 0; j < 8; ++j) cv[j] = s_dn[8 * cb + j] * inv;
#pragma unroll
        for (int i = 0; i < 8; ++i)
#pragma unroll
            for (int j = 0; j < 8; ++j) vals[i][j] -= rv[i] * cv[j];
        if (rb == pb) {
#pragma unroll
            for (int i = 0; i < 8; ++i) if (pi == i) {
#pragma unroll
                for (int j = 0; j < 8; ++j) vals[i][j] = cv[j];
            }
        }
        if (cb == pb) {
#pragma unroll
            for (int j = 0; j < 8; ++j) if (pi == j) {
#pragma unroll
                for (int i = 0; i < 8; ++i)
                    vals[i][j] = (rb == pb && pi == i) ? -inv : rv[i] * inv;
            }
        }
    }
#pragma unroll
    for (int i = 0; i < 8; ++i)
#pragma unroll
        for (int j = 0; j < 8; ++j)
            dst[(8 * rb + i) * NMEAS + 8 * cb + j] = -vals[i][j];
}

// ---------------------------------------------------------------------------
// fp64 Newton refinement:  P = Gd @ X ;  Xn = 2X - X @ P   (X input fp32/fp64)
// ---------------------------------------------------------------------------
template <typename TB>
__global__ __launch_bounds__(256) void mm_gd(const double* __restrict__ Gd,
                                             const TB* __restrict__ X,
                                             double* __restrict__ P) {
    __shared__ __align__(16) double row[NMEAS];
    int i = blockIdx.x;
    row[threadIdx.x] = Gd[i * NMEAS + threadIdx.x];
    __syncthreads();
    int j = threadIdx.x;
    double s = 0.0;
#pragma unroll 4
    for (int k = 0; k < NMEAS; ++k) s += row[k] * (double)X[k * NMEAS + j];
    P[i * NMEAS + j] = s;
}

template <typename TB>
__global__ __launch_bounds__(256) void upd_newton(const TB* __restrict__ X,
                                                  const double* __restrict__ P,
                                                  double* __restrict__ Xn) {
    __shared__ __align__(16) double row[NMEAS];
    int i = blockIdx.x;
    row[threadIdx.x] = (double)X[i * NMEAS + threadIdx.x];
    __syncthreads();
    int j = threadIdx.x;
    double s = 0.0;
#pragma unroll 4
    for (int k = 0; k < NMEAS; ++k) s += row[k] * P[k * NMEAS + j];
    Xn[i * NMEAS + j] = 2.0 * row[j] - s;
}

// ---------------------------------------------------------------------------
// K2: Hd = X2d @ A   (fp64 [256][256] @ fp32 [256][512] -> fp64 [256][512])
// ---------------------------------------------------------------------------
__global__ __launch_bounds__(256) void h_kernel_d(const double* __restrict__ Gi,
                                                  const float* __restrict__ A,
                                                  double* __restrict__ H) {
    __shared__ __align__(16) double grow[NMEAS];
    int i = blockIdx.x;
    grow[threadIdx.x] = Gi[i * NMEAS + threadIdx.x];
    __syncthreads();
    int k0 = threadIdx.x;
    double s0 = 0.0, s1 = 0.0;
#pragma unroll 4
    for (int j = 0; j < NMEAS; ++j) {
        double g = grow[j];
        s0 += g * (double)A[j * NATOMS + k0];
        s1 += g * (double)A[j * NATOMS + k0 + 256];
    }
    H[i * NATOMS + k0] = s0;
    H[i * NATOMS + k0 + 256] = s1;
}

// ---------------------------------------------------------------------------
// K3: W = I - A^T @ Hd  (fp64 accumulate), stored as bf16 hi/lo split
// ---------------------------------------------------------------------------
__global__ __launch_bounds__(256) void w_kernel_d(const float* __restrict__ A,
                                                  const double* __restrict__ H,
                                                  unsigned short* __restrict__ Whg,
                                                  unsigned short* __restrict__ Wlg) {
    __shared__ __align__(16) double acol[NMEAS];
    int p = blockIdx.x;
    acol[threadIdx.x] = (double)A[threadIdx.x * NATOMS + p];
    __syncthreads();
    int q0 = threadIdx.x;
    double s0 = 0.0, s1 = 0.0;
#pragma unroll 4
    for (int m = 0; m < NMEAS; ++m) {
        double a = acol[m];
        s0 += a * H[m * NATOMS + q0];
        s1 += a * H[m * NATOMS + q0 + 256];
    }
    double w0 = ((p == q0)       ? 1.0 : 0.0) - s0;
    double w1 = ((p == q0 + 256) ? 1.0 : 0.0) - s1;
    unsigned short h0 = f2bf((float)w0), h1 = f2bf((float)w1);
    Whg[p * NATOMS + q0]       = h0;
    Wlg[p * NATOMS + q0]       = f2bf((float)(w0 - (double)bf2f(h0)));
    Whg[p * NATOMS + q0 + 256] = h1;
    Wlg[p * NATOMS + q0 + 256] = f2bf((float)(w1 - (double)bf2f(h1)));
}

// ---------------------------------------------------------------------------
// K4: Delta0 = AtY (= t_1, since t_0 = 0), stored split bf16 hi/lo,
//     TRANSPOSED to [4096 voxels][512 atoms].
// AtY[k][b] = sum_m A[m][k] * Y[b][m]
// ---------------------------------------------------------------------------
__global__ __launch_bounds__(256) void aty_kernel(const float* __restrict__ A,
                                                  const float* __restrict__ Y,
                                                  unsigned short* __restrict__ Dh0,
                                                  unsigned short* __restrict__ Dl0) {
    __shared__ __align__(16) float At[64][65];
    __shared__ __align__(16) float Yt[64][65];
    int b0 = blockIdx.x * 64, k0 = blockIdx.y * 64;
    int t = threadIdx.x, tx = t & 15, ty = t >> 4;
    float acc[4][4] = {};
    for (int m0 = 0; m0 < NMEAS; m0 += 64) {
        __syncthreads();
        {
            int kk = t & 63, mr = t >> 6;
#pragma unroll
            for (int p = 0; p < 16; ++p)
                At[mr + 4 * p][kk] = A[(m0 + mr + 4 * p) * NATOMS + k0 + kk];
            int mm = t & 63, br = t >> 6;
#pragma unroll
            for (int p = 0; p < 16; ++p)
                Yt[mm][br + 4 * p] = Y[(b0 + br + 4 * p) * NMEAS + m0 + mm];
        }
        __syncthreads();
#pragma unroll 4
        for (int m = 0; m < 64; ++m) {
            float av[4], yv[4];
#pragma unroll
            for (int i = 0; i < 4; ++i) av[i] = At[m][ty * 4 + i];
#pragma unroll
            for (int j = 0; j < 4; ++j) yv[j] = Yt[m][tx * 4 + j];
#pragma unroll
            for (int i = 0; i < 4; ++i)
#pragma unroll
                for (int j = 0; j < 4; ++j) acc[i][j] += av[i] * yv[j];
        }
    }
#pragma unroll
    for (int j = 0; j < 4; ++j) {
        int b = b0 + tx * 4 + j;
        s4v h4, l4;
#pragma unroll
        for (int i = 0; i < 4; ++i) {
            float f = acc[i][j];
            unsigned short h = f2bf(f);
            h4[i] = (short)h;
            l4[i] = (short)f2bf(f - bf2f(h));
        }
        *(s4v*)&Dh0[(long)b * NATOMS + k0 + ty * 4] = h4;
        *(s4v*)&Dl0[(long)b * NATOMS + k0 + ty * 4] = l4;
    }
}

// ---------------------------------------------------------------------------
// K5: PERSISTENT fused ADMM v3 — all 30 iterations, one launch, 8 WAVES.
// r16 (v2, 256 thr) fixed the acc spill (VGPR 88) but ran at 4 waves/CU —
// latency-bound (Occupancy 11.8%, MfmaUtil 7.8%). v3: 512 threads / 8 waves,
// each wave owns 64 m-rows -> persistent acc[4] = 16 VGPR; peak live
// ~60 <= the hard 64-reg cap for 512-thr kernels (fits the cap instead of
// fighting it). Occupancy doubles; same L2 traffic.
// Block owns 16 voxels (grid 256 = 1/CU). Per iter:
//   acc (=x) += 3-term split GEMM over W (global, L2-resident)
//              x Delta (LDS chunk-major: wave B-read = 1KB contiguous)
//   epilogue: v' = x + min(v,0.1) (v in LDS); Delta' = g(v')-g(v) -> LDS
// 2 barriers/iter. Numerics bit-identical to r12/r13/r16 (absmax .00390625).
// LDS: Dh 16KB + Dl 16KB + v 33KB = 65KB.
// ---------------------------------------------------------------------------
__global__ __launch_bounds__(512) void admm_fused3(
        const unsigned short* __restrict__ Whg,
        const unsigned short* __restrict__ Wlg,
        const unsigned short* __restrict__ D0h,
        const unsigned short* __restrict__ D0l,
        float* __restrict__ out) {
    __shared__ __align__(16) unsigned short DhL[8192];  // chunk-major, 16KB
    __shared__ __align__(16) unsigned short DlL[8192];
    __shared__ __align__(16) float vL[16 * 516];        // [vox][atom] pitch 516

    const int t = threadIdx.x;
    const int lane = t & 63, wv = t >> 6;   // 8 waves
    const int ln = lane & 15, kg = lane >> 4;
    const long vb = (long)blockIdx.x * 16;  // this block's voxel base

    // ---- preload Delta_0 (global linear [vox][atom] -> chunk-major LDS)
#pragma unroll
    for (int q = 0; q < 2; ++q) {
        int u = q * 512 + t;                // 1024 s8v units per buffer
        int vox = u >> 6, a8 = u & 63;      // atom group a = a8*8
        int ldsU = ((a8 >> 2) * 16 + vox) * 4 + (a8 & 3);
        long g = (vb + vox) * NATOMS + a8 * 8;
        *(s8v*)&DhL[ldsU * 8] = *(const s8v*)&D0h[g];
        *(s8v*)&DlL[ldsU * 8] = *(const s8v*)&D0l[g];
    }
    for (int i = t; i < 16 * 516; i += 512) vL[i] = 0.0f;   // v0 = 0
    __syncthreads();

    f32x4 acc[4] = {};                      // x = MFMA accumulator (16 VGPR)

#pragma unroll 1
    for (int it = 0; it < NITER; ++it) {
        // ---- GEMM: acc += W @ Delta  (C-in = x_{k-1})
#pragma unroll 1
        for (int kc = 0; kc < 16; ++kc) {
            const int bidx = (((kc * 16 + ln) * 4) + kg) * 8;
            s8v bh = *(const s8v*)&DhL[bidx];
            s8v bl = *(const s8v*)&DlL[bidx];
            const int ko = kc * 32 + kg * 8;
#pragma unroll
            for (int mt = 0; mt < 4; ++mt) {
                const long row = (long)((wv * 4 + mt) * 16 + ln) * NATOMS + ko;
                s8v ah = *(const s8v*)&Whg[row];
                s8v al = *(const s8v*)&Wlg[row];
                acc[mt] = __builtin_amdgcn_mfma_f32_16x16x32_bf16(ah, bh, acc[mt], 0, 0, 0);
                acc[mt] = __builtin_amdgcn_mfma_f32_16x16x32_bf16(ah, bl, acc[mt], 0, 0, 0);
                acc[mt] = __builtin_amdgcn_mfma_f32_16x16x32_bf16(al, bh, acc[mt], 0, 0, 0);
            }
        }
        if (it == NITER - 1) break;         // acc holds x_30
        __syncthreads();                    // all waves done reading Delta
        // ---- epilogue: v' = x + min(v,0.1); Delta' = g(v')-g(v) -> LDS
#pragma unroll
        for (int mt = 0; mt < 4; ++mt) {
            int a0 = (wv * 4 + mt) * 16 + kg * 4;   // 4 consecutive atoms
            float* vp = &vL[ln * 516 + a0];
            f32x4 vo = *(const f32x4*)vp;
            f32x4 vn;
            s4v h4, l4;
#pragma unroll
            for (int j = 0; j < 4; ++j) {
                float x = acc[mt][j];
                float vnj = x + fminf(vo[j], 0.1f);
                float dlt = g_of(vnj) - g_of(vo[j]);
                vn[j] = vnj;
                unsigned short h = f2bf(dlt);
                h4[j] = (short)h;
                l4[j] = (short)f2bf(dlt - bf2f(h));
            }
            *(f32x4*)vp = vn;
            // chunk-major Delta store: a -> ((a>>5)*16+vox)*32 + ((a>>3)&3)*8 + (a&7)
            int lin = ((a0 >> 5) * 16 + ln) * 32 + ((a0 >> 3) & 3) * 8 + (a0 & 7);
            *(s4v*)&DhL[lin] = h4;
            *(s4v*)&DlL[lin] = l4;
        }
        __syncthreads();                    // Delta ready for next GEMM
    }
    // ---- final: out[vox][atom] = x_30 (float4 direct)
#pragma unroll
    for (int mt = 0; mt < 4; ++mt) {
        int a0 = (wv * 4 + mt) * 16 + kg * 4;
        *(f32x4*)&out[(vb + ln) * NATOMS + a0] = acc[mt];
    }
}

// ---------------------------------------------------------------------------
extern "C" void kernel_launch(void* const* d_in, const int* in_sizes, int n_in,
                              void* d_out, int out_size, void* d_ws, size_t ws_size,
                              hipStream_t stream) {
    const float* Y = (const float*)d_in[0];   // [4096][256]
    const float* A = (const float*)d_in[1];   // [256][512]

    // ws layout (float units), lifetime-checked overlays (r3-r16 footprint).
    float* ws = (float*)d_ws;
    double* Gd  = (double*)(ws + 0);        // [0,131072)       dead after step 5
    float*  Gf  = ws + 131072;              // [131072,196608)  dead after sweep
    float*  X0f = ws + 196608;              // [196608,262144)  dead after step 4
    double* X1d = (double*)(ws + 262144);   // [262144,393216)  dead after step 6
    double* Pd  = (double*)(ws + 393216);   // [393216,524288)  dead after step 6
    double* X2d = (double*)(ws + 131072);   // overlays Gf+X0f (both dead)
    double* Hd  = (double*)(ws + 393216);   // [393216,655360) overlays Pd (dead)
    unsigned short* Whg = (unsigned short*)(ws + 0);        // overlays Gd (dead)
    unsigned short* Wlg = (unsigned short*)(ws + 131072);   // overlays X2d (dead after h)
    unsigned short* DAh = (unsigned short*)(ws + 2752512);  // Delta_0 hi
    unsigned short* DAl = (unsigned short*)(ws + 3801088);  // Delta_0 lo
    float* outp = (float*)d_out;

    g_kernel_d<<<256, 256, 0, stream>>>(A, Gd, Gf);                 // 1
    sweep_inverse<<<1, 1024, 0, stream>>>(Gf, X0f);                 // 2
    mm_gd<float><<<256, 256, 0, stream>>>(Gd, X0f, Pd);             // 3
    upd_newton<float><<<256, 256, 0, stream>>>(X0f, Pd, X1d);       // 4
    mm_gd<double><<<256, 256, 0, stream>>>(Gd, X1d, Pd);            // 5
    upd_newton<double><<<256, 256, 0, stream>>>(X1d, Pd, X2d);      // 6
    h_kernel_d<<<256, 256, 0, stream>>>(X2d, A, Hd);                // 7
    w_kernel_d<<<512, 256, 0, stream>>>(A, Hd, Whg, Wlg);           // 8
    aty_kernel<<<dim3(64, 8), 256, 0, stream>>>(A, Y, DAh, DAl);    // 9

    // 10: all 30 ADMM iterations, one persistent launch (256 blocks x 16 vox,
    //     512 thr / 8 waves)
    admm_fused3<<<256, 512, 0, stream>>>(Whg, Wlg, DAh, DAl, outp);
}

// Round 19
// 946.531 us; speedup vs baseline: 1.4978x; 1.4235x over previous
//
#include <hip/hip_runtime.h>

// Problem constants (from reference setup_inputs)
#define NVOX   4096   // B voxels
#define NMEAS  256    // M measurements
#define NATOMS 512    // K atoms
#define NITER  30

typedef __attribute__((ext_vector_type(8))) short s8v;   // 8 bf16 (4 VGPR) MFMA frag
typedef __attribute__((ext_vector_type(4))) short s4v;
typedef __attribute__((ext_vector_type(4))) float f32x4;

// bf16 round-to-nearest-even split helpers (no NaN/Inf in this problem)
__device__ __forceinline__ unsigned short f2bf(float x) {
    unsigned u = __builtin_bit_cast(unsigned, x);
    u += 0x7fff + ((u >> 16) & 1);
    return (unsigned short)(u >> 16);
}
__device__ __forceinline__ float bf2f(unsigned short b) {
    unsigned u = ((unsigned)b) << 16;
    return __builtin_bit_cast(float, u);
}
// g(v) = (z - u) collapsed through v = x + u :  relu(v-0.1) - min(v,0.1)
__device__ __forceinline__ float g_of(float v) {
    return fmaxf(v - 0.1f, 0.0f) - fminf(v, 0.1f);
}

// Swizzled streaming layout for W: element (p=row,q=col) lives at
// idx = ((((p>>4)*16 + (q>>5))*16 + (p&15))*4 + ((q>>3)&3))*8 + (q&7)
// i.e. block (tile=p>>4, kc=q>>5) of 512 shorts (1KB), lane (ln=p&15,
// kg=(q>>3)&3) at ln*32+kg*8. A wave's (tile,kc) read is ONE contiguous
// 1KB block; consecutive kc are sequential -> channel-balanced L2 streams.
// r18 BUG: reader used stride 1024 (the comment's "2KB") while this writer
// packs 512-short blocks -> OOB reads -> NaN. r19 fix: reader stride 512.
__device__ __forceinline__ int wswz(int p, int q) {
    return ((((p >> 4) * 16 + (q >> 5)) * 16 + (p & 15)) * 4 + ((q >> 3) & 3)) * 8 + (q & 7);
}

// ---------------------------------------------------------------------------
// K0: G = I + A*A^T in fp64 (Gd) + fp32 copy (Gf) for the sweep
// ---------------------------------------------------------------------------
__global__ __launch_bounds__(256) void g_kernel_d(const float* __restrict__ A,
                                                  double* __restrict__ Gd,
                                                  float* __restrict__ Gf) {
    __shared__ float arow[NATOMS];
    int i = blockIdx.x;
    for (int k = threadIdx.x; k < NATOMS; k += 256) arow[k] = A[i * NATOMS + k];
    __syncthreads();
    int j = threadIdx.x;
    const float* aj = A + j * NATOMS;
    double s = (i == j) ? 1.0 : 0.0;
#pragma unroll 4
    for (int k = 0; k < NATOMS; ++k) s += (double)arow[k] * (double)aj[k];
    Gd[i * NMEAS + j] = s;
    Gf[i * NMEAS + j] = (float)s;
}

// ---------------------------------------------------------------------------
// K1: SPD inverse of Gf (256x256) via scalar symmetric SWEEP — r5-proven,
// 283us structural floor (r6/r7/r9/r14 blocked variants all spilled).
// sweep(all) = -G^{-1}; negate on store.
// ---------------------------------------------------------------------------
__global__ __launch_bounds__(1024) void sweep_inverse(const float* __restrict__ src,
                                                      float* __restrict__ dst) {
    __shared__ float s_dn[NMEAS];
    __shared__ float s_dt[NMEAS];
    int t = threadIdx.x;
    int rb = t & 31;
    int cb = t >> 5;
    float vals[8][8];
#pragma unroll
    for (int i = 0; i < 8; ++i) {
        const float* row = &src[(8 * rb + i) * NMEAS + 8 * cb];
        float4 a = *(const float4*)row;
        float4 b = *(const float4*)(row + 4);
        vals[i][0] = a.x; vals[i][1] = a.y; vals[i][2] = a.z; vals[i][3] = a.w;
        vals[i][4] = b.x; vals[i][5] = b.y; vals[i][6] = b.z; vals[i][7] = b.w;
    }
#pragma unroll 1
    for (int p = 0; p < NMEAS; ++p) {
        int pb = p >> 3, pi = p & 7;
        __syncthreads();
        if (cb == pb) {
#pragma unroll
            for (int i = 0; i < 8; ++i) {
                float v = vals[i][0];
#pragma unroll
                for (int j = 1; j < 8; ++j) if (pi == j) v = vals[i][j];
                s_dn[8 * rb + i] = v;
                s_dt[i * 32 + rb] = v;
            }
        }
        __syncthreads();
        float d   = s_dn[p];
        float inv = 1.0f / d;
        float rv[8], cv[8];
#pragma unroll
        for (int i = 0; i < 8; ++i) rv[i] = s_dt[i * 32 + rb];
#pragma unroll
        for (int j = 0; j < 8; ++j) cv[j] = s_dn[8 * cb + j] * inv;
#pragma unroll
        for (int i = 0; i < 8; ++i)
#pragma unroll
            for (int j = 0; j < 8; ++j) vals[i][j] -= rv[i] * cv[j];
        if (rb == pb) {
#pragma unroll
            for (int i = 0; i < 8; ++i) if (pi == i) {
#pragma unroll
                for (int j = 0; j < 8; ++j) vals[i][j] = cv[j];
            }
        }
        if (cb == pb) {
#pragma unroll
            for (int j = 0; j < 8; ++j) if (pi == j) {
#pragma unroll
                for (int i = 0; i < 8; ++i)
                    vals[i][j] = (rb == pb && pi == i) ? -inv : rv[i] * inv;
            }
        }
    }
#pragma unroll
    for (int i = 0; i < 8; ++i)
#pragma unroll
        for (int j = 0; j < 8; ++j)
            dst[(8 * rb + i) * NMEAS + 8 * cb + j] = -vals[i][j];
}

// ---------------------------------------------------------------------------
// fp64 Newton refinement:  P = Gd @ X ;  Xn = 2X - X @ P   (X input fp32/fp64)
// ---------------------------------------------------------------------------
template <typename TB>
__global__ __launch_bounds__(256) void mm_gd(const double* __restrict__ Gd,
                                             const TB* __restrict__ X,
                                             double* __restrict__ P) {
    __shared__ __align__(16) double row[NMEAS];
    int i = blockIdx.x;
    row[threadIdx.x] = Gd[i * NMEAS + threadIdx.x];
    __syncthreads();
    int j = threadIdx.x;
    double s = 0.0;
#pragma unroll 4
    for (int k = 0; k < NMEAS; ++k) s += row[k] * (double)X[k * NMEAS + j];
    P[i * NMEAS + j] = s;
}

template <typename TB>
__global__ __launch_bounds__(256) void upd_newton(const TB* __restrict__ X,
                                                  const double* __restrict__ P,
                                                  double* __restrict__ Xn) {
    __shared__ __align__(16) double row[NMEAS];
    int i = blockIdx.x;
    row[threadIdx.x] = (double)X[i * NMEAS + threadIdx.x];
    __syncthreads();
    int j = threadIdx.x;
    double s = 0.0;
#pragma unroll 4
    for (int k = 0; k < NMEAS; ++k) s += row[k] * P[k * NMEAS + j];
    Xn[i * NMEAS + j] = 2.0 * row[j] - s;
}

// ---------------------------------------------------------------------------
// K2: Hd = X2d @ A   (fp64 [256][256] @ fp32 [256][512] -> fp64 [256][512])
// ---------------------------------------------------------------------------
__global__ __launch_bounds__(256) void h_kernel_d(const double* __restrict__ Gi,
                                                  const float* __restrict__ A,
                                                  double* __restrict__ H) {
    __shared__ __align__(16) double grow[NMEAS];
    int i = blockIdx.x;
    grow[threadIdx.x] = Gi[i * NMEAS + threadIdx.x];
    __syncthreads();
    int k0 = threadIdx.x;
    double s0 = 0.0, s1 = 0.0;
#pragma unroll 4
    for (int j = 0; j < NMEAS; ++j) {
        double g = grow[j];
        s0 += g * (double)A[j * NATOMS + k0];
        s1 += g * (double)A[j * NATOMS + k0 + 256];
    }
    H[i * NATOMS + k0] = s0;
    H[i * NATOMS + k0 + 256] = s1;
}

// ---------------------------------------------------------------------------
// K3: W = I - A^T @ Hd  (fp64 accumulate), stored bf16 hi/lo in the
// SWIZZLED streaming layout (consumed only by admm_fused3).
// ---------------------------------------------------------------------------
__global__ __launch_bounds__(256) void w_kernel_d(const float* __restrict__ A,
                                                  const double* __restrict__ H,
                                                  unsigned short* __restrict__ Whg,
                                                  unsigned short* __restrict__ Wlg) {
    __shared__ __align__(16) double acol[NMEAS];
    int p = blockIdx.x;
    acol[threadIdx.x] = (double)A[threadIdx.x * NATOMS + p];
    __syncthreads();
    int q0 = threadIdx.x;
    double s0 = 0.0, s1 = 0.0;
#pragma unroll 4
    for (int m = 0; m < NMEAS; ++m) {
        double a = acol[m];
        s0 += a * H[m * NATOMS + q0];
        s1 += a * H[m * NATOMS + q0 + 256];
    }
    double w0 = ((p == q0)       ? 1.0 : 0.0) - s0;
    double w1 = ((p == q0 + 256) ? 1.0 : 0.0) - s1;
    unsigned short h0 = f2bf((float)w0), h1 = f2bf((float)w1);
    int i0 = wswz(p, q0), i1 = wswz(p, q0 + 256);
    Whg[i0] = h0;
    Wlg[i0] = f2bf((float)(w0 - (double)bf2f(h0)));
    Whg[i1] = h1;
    Wlg[i1] = f2bf((float)(w1 - (double)bf2f(h1)));
}

// ---------------------------------------------------------------------------
// K4: Delta0 = AtY (= t_1, since t_0 = 0), stored split bf16 hi/lo,
//     TRANSPOSED to [4096 voxels][512 atoms].
// AtY[k][b] = sum_m A[m][k] * Y[b][m]
// ---------------------------------------------------------------------------
__global__ __launch_bounds__(256) void aty_kernel(const float* __restrict__ A,
                                                  const float* __restrict__ Y,
                                                  unsigned short* __restrict__ Dh0,
                                                  unsigned short* __restrict__ Dl0) {
    __shared__ __align__(16) float At[64][65];
    __shared__ __align__(16) float Yt[64][65];
    int b0 = blockIdx.x * 64, k0 = blockIdx.y * 64;
    int t = threadIdx.x, tx = t & 15, ty = t >> 4;
    float acc[4][4] = {};
    for (int m0 = 0; m0 < NMEAS; m0 += 64) {
        __syncthreads();
        {
            int kk = t & 63, mr = t >> 6;
#pragma unroll
            for (int p = 0; p < 16; ++p)
                At[mr + 4 * p][kk] = A[(m0 + mr + 4 * p) * NATOMS + k0 + kk];
            int mm = t & 63, br = t >> 6;
#pragma unroll
            for (int p = 0; p < 16; ++p)
                Yt[mm][br + 4 * p] = Y[(b0 + br + 4 * p) * NMEAS + m0 + mm];
        }
        __syncthreads();
#pragma unroll 4
        for (int m = 0; m < 64; ++m) {
            float av[4], yv[4];
#pragma unroll
            for (int i = 0; i < 4; ++i) av[i] = At[m][ty * 4 + i];
#pragma unroll
            for (int j = 0; j < 4; ++j) yv[j] = Yt[m][tx * 4 + j];
#pragma unroll
            for (int i = 0; i < 4; ++i)
#pragma unroll
                for (int j = 0; j < 4; ++j) acc[i][j] += av[i] * yv[j];
        }
    }
#pragma unroll
    for (int j = 0; j < 4; ++j) {
        int b = b0 + tx * 4 + j;
        s4v h4, l4;
#pragma unroll
        for (int i = 0; i < 4; ++i) {
            float f = acc[i][j];
            unsigned short h = f2bf(f);
            h4[i] = (short)h;
            l4[i] = (short)f2bf(f - bf2f(h));
        }
        *(s4v*)&Dh0[(long)b * NATOMS + k0 + ty * 4] = h4;
        *(s4v*)&Dl0[(long)b * NATOMS + k0 + ty * 4] = l4;
    }
}

// ---------------------------------------------------------------------------
// K5: PERSISTENT fused ADMM v3 + swizzled-W streaming (r19 = r18 with the
// reader stride corrected 1024 -> 512 to match wswz's 512-short blocks).
// r17 diagnosis: L2-BW bound at 47% efficiency — a wave's W-read touched 16
// lines at 1KB stride (channel contention). Swizzled layout: each (tile,kc)
// W-read is one contiguous 1KB block, consecutive kc sequential ->
// full-line, channel-balanced streams. Values bit-identical.
// Structure: 512thr/8 waves, block owns 16 voxels, acc[4]=x (16 VGPR
// persistent, VGPR=52 no-spill), v in LDS, Delta in LDS chunk-major,
// 2 barriers/iter. absmax 0.00390625 across r12-r17.
// ---------------------------------------------------------------------------
__global__ __launch_bounds__(512) void admm_fused3(
        const unsigned short* __restrict__ Whg,
        const unsigned short* __restrict__ Wlg,
        const unsigned short* __restrict__ D0h,
        const unsigned short* __restrict__ D0l,
        float* __restrict__ out) {
    __shared__ __align__(16) unsigned short DhL[8192];  // chunk-major, 16KB
    __shared__ __align__(16) unsigned short DlL[8192];
    __shared__ __align__(16) float vL[16 * 516];        // [vox][atom] pitch 516

    const int t = threadIdx.x;
    const int lane = t & 63, wv = t >> 6;   // 8 waves
    const int ln = lane & 15, kg = lane >> 4;
    const long vb = (long)blockIdx.x * 16;  // this block's voxel base

    // ---- preload Delta_0 (global linear [vox][atom] -> chunk-major LDS)
#pragma unroll
    for (int q = 0; q < 2; ++q) {
        int u = q * 512 + t;                // 1024 s8v units per buffer
        int vox = u >> 6, a8 = u & 63;      // atom group a = a8*8
        int ldsU = ((a8 >> 2) * 16 + vox) * 4 + (a8 & 3);
        long g = (vb + vox) * NATOMS + a8 * 8;
        *(s8v*)&DhL[ldsU * 8] = *(const s8v*)&D0h[g];
        *(s8v*)&DlL[ldsU * 8] = *(const s8v*)&D0l[g];
    }
    for (int i = t; i < 16 * 516; i += 512) vL[i] = 0.0f;   // v0 = 0
    __syncthreads();

    f32x4 acc[4] = {};                      // x = MFMA accumulator (16 VGPR)

#pragma unroll 1
    for (int it = 0; it < NITER; ++it) {
        // ---- GEMM: acc += W @ Delta  (C-in = x_{k-1})
#pragma unroll 1
        for (int kc = 0; kc < 16; ++kc) {
            const int bidx = (((kc * 16 + ln) * 4) + kg) * 8;
            s8v bh = *(const s8v*)&DhL[bidx];
            s8v bl = *(const s8v*)&DlL[bidx];
            const int lanoff = ln * 32 + kg * 8;   // lane offset in 1KB block
#pragma unroll
            for (int mt = 0; mt < 4; ++mt) {
                const int tile = wv * 4 + mt;
                const int off = (tile * 16 + kc) * 512 + lanoff;   // r19 fix
                s8v ah = *(const s8v*)&Whg[off];
                s8v al = *(const s8v*)&Wlg[off];
                acc[mt] = __builtin_amdgcn_mfma_f32_16x16x32_bf16(ah, bh, acc[mt], 0, 0, 0);
                acc[mt] = __builtin_amdgcn_mfma_f32_16x16x32_bf16(ah, bl, acc[mt], 0, 0, 0);
                acc[mt] = __builtin_amdgcn_mfma_f32_16x16x32_bf16(al, bh, acc[mt], 0, 0, 0);
            }
        }
        if (it == NITER - 1) break;         // acc holds x_30
        __syncthreads();                    // all waves done reading Delta
        // ---- epilogue: v' = x + min(v,0.1); Delta' = g(v')-g(v) -> LDS
#pragma unroll
        for (int mt = 0; mt < 4; ++mt) {
            int a0 = (wv * 4 + mt) * 16 + kg * 4;   // 4 consecutive atoms
            float* vp = &vL[ln * 516 + a0];
            f32x4 vo = *(const f32x4*)vp;
            f32x4 vn;
            s4v h4, l4;
#pragma unroll
            for (int j = 0; j < 4; ++j) {
                float x = acc[mt][j];
                float vnj = x + fminf(vo[j], 0.1f);
                float dlt = g_of(vnj) - g_of(vo[j]);
                vn[j] = vnj;
                unsigned short h = f2bf(dlt);
                h4[j] = (short)h;
                l4[j] = (short)f2bf(dlt - bf2f(h));
            }
            *(f32x4*)vp = vn;
            // chunk-major Delta store: a -> ((a>>5)*16+vox)*32 + ((a>>3)&3)*8 + (a&7)
            int lin = ((a0 >> 5) * 16 + ln) * 32 + ((a0 >> 3) & 3) * 8 + (a0 & 7);
            *(s4v*)&DhL[lin] = h4;
            *(s4v*)&DlL[lin] = l4;
        }
        __syncthreads();                    // Delta ready for next GEMM
    }
    // ---- final: out[vox][atom] = x_30 (float4 direct)
#pragma unroll
    for (int mt = 0; mt < 4; ++mt) {
        int a0 = (wv * 4 + mt) * 16 + kg * 4;
        *(f32x4*)&out[(vb + ln) * NATOMS + a0] = acc[mt];
    }
}

// ---------------------------------------------------------------------------
extern "C" void kernel_launch(void* const* d_in, const int* in_sizes, int n_in,
                              void* d_out, int out_size, void* d_ws, size_t ws_size,
                              hipStream_t stream) {
    const float* Y = (const float*)d_in[0];   // [4096][256]
    const float* A = (const float*)d_in[1];   // [256][512]

    // ws layout (float units), lifetime-checked overlays (r3-r18 footprint).
    float* ws = (float*)d_ws;
    double* Gd  = (double*)(ws + 0);        // [0,131072)       dead after step 5
    float*  Gf  = ws + 131072;              // [131072,196608)  dead after sweep
    float*  X0f = ws + 196608;              // [196608,262144)  dead after step 4
    double* X1d = (double*)(ws + 262144);   // [262144,393216)  dead after step 6
    double* Pd  = (double*)(ws + 393216);   // [393216,524288)  dead after step 6
    double* X2d = (double*)(ws + 131072);   // overlays Gf+X0f (both dead)
    double* Hd  = (double*)(ws + 393216);   // [393216,655360) overlays Pd (dead)
    unsigned short* Whg = (unsigned short*)(ws + 0);        // overlays Gd (dead)
    unsigned short* Wlg = (unsigned short*)(ws + 131072);   // overlays X2d (dead after h)
    unsigned short* DAh = (unsigned short*)(ws + 2752512);  // Delta_0 hi
    unsigned short* DAl = (unsigned short*)(ws + 3801088);  // Delta_0 lo
    float* outp = (float*)d_out;

    g_kernel_d<<<256, 256, 0, stream>>>(A, Gd, Gf);                 // 1
    sweep_inverse<<<1, 1024, 0, stream>>>(Gf, X0f);                 // 2
    mm_gd<float><<<256, 256, 0, stream>>>(Gd, X0f, Pd);             // 3
    upd_newton<float><<<256, 256, 0, stream>>>(X0f, Pd, X1d);       // 4
    mm_gd<double><<<256, 256, 0, stream>>>(Gd, X1d, Pd);            // 5
    upd_newton<double><<<256, 256, 0, stream>>>(X1d, Pd, X2d);      // 6
    h_kernel_d<<<256, 256, 0, stream>>>(X2d, A, Hd);                // 7
    w_kernel_d<<<512, 256, 0, stream>>>(A, Hd, Whg, Wlg);           // 8
    aty_kernel<<<dim3(64, 8), 256, 0, stream>>>(A, Y, DAh, DAl);    // 9

    // 10: all 30 ADMM iterations, one persistent launch (256 blocks x 16 vox,
    //     512 thr / 8 waves, swizzled-W streaming)
    admm_fused3<<<256, 512, 0, stream>>>(Whg, Wlg, DAh, DAl, outp);
}

// Round 20
// 923.777 us; speedup vs baseline: 1.5347x; 1.0246x over previous
//
#include <hip/hip_runtime.h>

// Problem constants (from reference setup_inputs)
#define NVOX   4096   // B voxels
#define NMEAS  256    // M measurements
#define NATOMS 512    // K atoms
#define NITER  30

typedef __attribute__((ext_vector_type(8))) short s8v;   // 8 bf16 (4 VGPR) MFMA frag
typedef __attribute__((ext_vector_type(4))) short s4v;
typedef __attribute__((ext_vector_type(4))) float f32x4;

// bf16 round-to-nearest-even split helpers (no NaN/Inf in this problem)
__device__ __forceinline__ unsigned short f2bf(float x) {
    unsigned u = __builtin_bit_cast(unsigned, x);
    u += 0x7fff + ((u >> 16) & 1);
    return (unsigned short)(u >> 16);
}
__device__ __forceinline__ float bf2f(unsigned short b) {
    unsigned u = ((unsigned)b) << 16;
    return __builtin_bit_cast(float, u);
}
// g(v) = (z - u) collapsed through v = x + u :  relu(v-0.1) - min(v,0.1)
__device__ __forceinline__ float g_of(float v) {
    return fmaxf(v - 0.1f, 0.0f) - fminf(v, 0.1f);
}

// Swizzled streaming layout for W: element (p=row,q=col) lives at
// idx = ((((p>>4)*16 + (q>>5))*16 + (p&15))*4 + ((q>>3)&3))*8 + (q&7)
// i.e. block (tile=p>>4, kc=q>>5) of 512 shorts (1KB), lane (ln=p&15,
// kg=(q>>3)&3) at ln*32+kg*8. A wave's (tile,kc) read is ONE contiguous
// 1KB block; consecutive kc sequential -> channel-balanced L2 streams.
// (r19-proven: fused 940 -> 538us.)
__device__ __forceinline__ int wswz(int p, int q) {
    return ((((p >> 4) * 16 + (q >> 5)) * 16 + (p & 15)) * 4 + ((q >> 3) & 3)) * 8 + (q & 7);
}

// ---------------------------------------------------------------------------
// K0: G = I + A*A^T in fp64 (Gd) + fp32 copy (Gf) for the sweep
// ---------------------------------------------------------------------------
__global__ __launch_bounds__(256) void g_kernel_d(const float* __restrict__ A,
                                                  double* __restrict__ Gd,
                                                  float* __restrict__ Gf) {
    __shared__ float arow[NATOMS];
    int i = blockIdx.x;
    for (int k = threadIdx.x; k < NATOMS; k += 256) arow[k] = A[i * NATOMS + k];
    __syncthreads();
    int j = threadIdx.x;
    const float* aj = A + j * NATOMS;
    double s = (i == j) ? 1.0 : 0.0;
#pragma unroll 4
    for (int k = 0; k < NATOMS; ++k) s += (double)arow[k] * (double)aj[k];
    Gd[i * NMEAS + j] = s;
    Gf[i * NMEAS + j] = (float)s;
}

// ---------------------------------------------------------------------------
// K1: SPD inverse of Gf (256x256) via scalar symmetric SWEEP — r5-proven,
// 283us structural floor (r6/r7/r9/r14 blocked variants all spilled).
// sweep(all) = -G^{-1}; negate on store.
// ---------------------------------------------------------------------------
__global__ __launch_bounds__(1024) void sweep_inverse(const float* __restrict__ src,
                                                      float* __restrict__ dst) {
    __shared__ float s_dn[NMEAS];
    __shared__ float s_dt[NMEAS];
    int t = threadIdx.x;
    int rb = t & 31;
    int cb = t >> 5;
    float vals[8][8];
#pragma unroll
    for (int i = 0; i < 8; ++i) {
        const float* row = &src[(8 * rb + i) * NMEAS + 8 * cb];
        float4 a = *(const float4*)row;
        float4 b = *(const float4*)(row + 4);
        vals[i][0] = a.x; vals[i][1] = a.y; vals[i][2] = a.z; vals[i][3] = a.w;
        vals[i][4] = b.x; vals[i][5] = b.y; vals[i][6] = b.z; vals[i][7] = b.w;
    }
#pragma unroll 1
    for (int p = 0; p < NMEAS; ++p) {
        int pb = p >> 3, pi = p & 7;
        __syncthreads();
        if (cb == pb) {
#pragma unroll
            for (int i = 0; i < 8; ++i) {
                float v = vals[i][0];
#pragma unroll
                for (int j = 1; j < 8; ++j) if (pi == j) v = vals[i][j];
                s_dn[8 * rb + i] = v;
                s_dt[i * 32 + rb] = v;
            }
        }
        __syncthreads();
        float d   = s_dn[p];
        float inv = 1.0f / d;
        float rv[8], cv[8];
#pragma unroll
        for (int i = 0; i < 8; ++i) rv[i] = s_dt[i * 32 + rb];
#pragma unroll
        for (int j = 0; j < 8; ++j) cv[j] = s_dn[8 * cb + j] * inv;
#pragma unroll
        for (int i = 0; i < 8; ++i)
#pragma unroll
            for (int j = 0; j < 8; ++j) vals[i][j] -= rv[i] * cv[j];
        if (rb == pb) {
#pragma unroll
            for (int i = 0; i < 8; ++i) if (pi == i) {
#pragma unroll
                for (int j = 0; j < 8; ++j) vals[i][j] = cv[j];
            }
        }
        if (cb == pb) {
#pragma unroll
            for (int j = 0; j < 8; ++j) if (pi == j) {
#pragma unroll
                for (int i = 0; i < 8; ++i)
                    vals[i][j] = (rb == pb && pi == i) ? -inv : rv[i] * inv;
            }
        }
    }
#pragma unroll
    for (int i = 0; i < 8; ++i)
#pragma unroll
        for (int j = 0; j < 8; ++j)
            dst[(8 * rb + i) * NMEAS + 8 * cb + j] = -vals[i][j];
}

// ---------------------------------------------------------------------------
// fp64 Newton refinement:  P = Gd @ X ;  Xn = 2X - X @ P   (X input fp32/fp64)
// ---------------------------------------------------------------------------
template <typename TB>
__global__ __launch_bounds__(256) void mm_gd(const double* __restrict__ Gd,
                                             const TB* __restrict__ X,
                                             double* __restrict__ P) {
    __shared__ __align__(16) double row[NMEAS];
    int i = blockIdx.x;
    row[threadIdx.x] = Gd[i * NMEAS + threadIdx.x];
    __syncthreads();
    int j = threadIdx.x;
    double s = 0.0;
#pragma unroll 4
    for (int k = 0; k < NMEAS; ++k) s += row[k] * (double)X[k * NMEAS + j];
    P[i * NMEAS + j] = s;
}

template <typename TB>
__global__ __launch_bounds__(256) void upd_newton(const TB* __restrict__ X,
                                                  const double* __restrict__ P,
                                                  double* __restrict__ Xn) {
    __shared__ __align__(16) double row[NMEAS];
    int i = blockIdx.x;
    row[threadIdx.x] = (double)X[i * NMEAS + threadIdx.x];
    __syncthreads();
    int j = threadIdx.x;
    double s = 0.0;
#pragma unroll 4
    for (int k = 0; k < NMEAS; ++k) s += row[k] * P[k * NMEAS + j];
    Xn[i * NMEAS + j] = 2.0 * row[j] - s;
}

// ---------------------------------------------------------------------------
// K2: Hd = X2d @ A   (fp64 [256][256] @ fp32 [256][512] -> fp64 [256][512])
// ---------------------------------------------------------------------------
__global__ __launch_bounds__(256) void h_kernel_d(const double* __restrict__ Gi,
                                                  const float* __restrict__ A,
                                                  double* __restrict__ H) {
    __shared__ __align__(16) double grow[NMEAS];
    int i = blockIdx.x;
    grow[threadIdx.x] = Gi[i * NMEAS + threadIdx.x];
    __syncthreads();
    int k0 = threadIdx.x;
    double s0 = 0.0, s1 = 0.0;
#pragma unroll 4
    for (int j = 0; j < NMEAS; ++j) {
        double g = grow[j];
        s0 += g * (double)A[j * NATOMS + k0];
        s1 += g * (double)A[j * NATOMS + k0 + 256];
    }
    H[i * NATOMS + k0] = s0;
    H[i * NATOMS + k0 + 256] = s1;
}

// ---------------------------------------------------------------------------
// K3: W = I - A^T @ Hd  (fp64 accumulate), stored bf16 hi/lo in the
// SWIZZLED streaming layout (consumed only by the fused kernel).
// ---------------------------------------------------------------------------
__global__ __launch_bounds__(256) void w_kernel_d(const float* __restrict__ A,
                                                  const double* __restrict__ H,
                                                  unsigned short* __restrict__ Whg,
                                                  unsigned short* __restrict__ Wlg) {
    __shared__ __align__(16) double acol[NMEAS];
    int p = blockIdx.x;
    acol[threadIdx.x] = (double)A[threadIdx.x * NATOMS + p];
    __syncthreads();
    int q0 = threadIdx.x;
    double s0 = 0.0, s1 = 0.0;
#pragma unroll 4
    for (int m = 0; m < NMEAS; ++m) {
        double a = acol[m];
        s0 += a * H[m * NATOMS + q0];
        s1 += a * H[m * NATOMS + q0 + 256];
    }
    double w0 = ((p == q0)       ? 1.0 : 0.0) - s0;
    double w1 = ((p == q0 + 256) ? 1.0 : 0.0) - s1;
    unsigned short h0 = f2bf((float)w0), h1 = f2bf((float)w1);
    int i0 = wswz(p, q0), i1 = wswz(p, q0 + 256);
    Whg[i0] = h0;
    Wlg[i0] = f2bf((float)(w0 - (double)bf2f(h0)));
    Whg[i1] = h1;
    Wlg[i1] = f2bf((float)(w1 - (double)bf2f(h1)));
}

// ---------------------------------------------------------------------------
// K4: Delta0 = AtY (= t_1, since t_0 = 0), stored split bf16 hi/lo,
//     TRANSPOSED to [4096 voxels][512 atoms].
// AtY[k][b] = sum_m A[m][k] * Y[b][m]
// ---------------------------------------------------------------------------
__global__ __launch_bounds__(256) void aty_kernel(const float* __restrict__ A,
                                                  const float* __restrict__ Y,
                                                  unsigned short* __restrict__ Dh0,
                                                  unsigned short* __restrict__ Dl0) {
    __shared__ __align__(16) float At[64][65];
    __shared__ __align__(16) float Yt[64][65];
    int b0 = blockIdx.x * 64, k0 = blockIdx.y * 64;
    int t = threadIdx.x, tx = t & 15, ty = t >> 4;
    float acc[4][4] = {};
    for (int m0 = 0; m0 < NMEAS; m0 += 64) {
        __syncthreads();
        {
            int kk = t & 63, mr = t >> 6;
#pragma unroll
            for (int p = 0; p < 16; ++p)
                At[mr + 4 * p][kk] = A[(m0 + mr + 4 * p) * NATOMS + k0 + kk];
            int mm = t & 63, br = t >> 6;
#pragma unroll
            for (int p = 0; p < 16; ++p)
                Yt[mm][br + 4 * p] = Y[(b0 + br + 4 * p) * NMEAS + m0 + mm];
        }
        __syncthreads();
#pragma unroll 4
        for (int m = 0; m < 64; ++m) {
            float av[4], yv[4];
#pragma unroll
            for (int i = 0; i < 4; ++i) av[i] = At[m][ty * 4 + i];
#pragma unroll
            for (int j = 0; j < 4; ++j) yv[j] = Yt[m][tx * 4 + j];
#pragma unroll
            for (int i = 0; i < 4; ++i)
#pragma unroll
                for (int j = 0; j < 4; ++j) acc[i][j] += av[i] * yv[j];
        }
    }
#pragma unroll
    for (int j = 0; j < 4; ++j) {
        int b = b0 + tx * 4 + j;
        s4v h4, l4;
#pragma unroll
        for (int i = 0; i < 4; ++i) {
            float f = acc[i][j];
            unsigned short h = f2bf(f);
            h4[i] = (short)h;
            l4[i] = (short)f2bf(f - bf2f(h));
        }
        *(s4v*)&Dh0[(long)b * NATOMS + k0 + ty * 4] = h4;
        *(s4v*)&Dl0[(long)b * NATOMS + k0 + ty * 4] = l4;
    }
}

// ---------------------------------------------------------------------------
// K5: PERSISTENT fused ADMM v4 — swizzled-W streaming + REGISTER PREFETCH.
// r19 (512thr, no prefetch) hit 538us: ~2.6x above the per-CU L2-BW floor
// with both pipes idle -> exposed L2 latency (loads consumed synchronously,
// only 2 waves/SIMD). v4: 256-thr blocks (allocator grants >64 VGPR: r16=88,
// m97=164; 512-thr pins at 64 -> no prefetch headroom) with wave-owned
// 8 tiles split in two groups of 4; two NAMED W-frag buffers ping-pong
// (compile-time indices, rule #20): group B's 8 loads are in flight while
// group A's 12 MFMAs execute -> ~32KB/CU outstanding > Little's-law 19KB.
// Per-acc MFMA sequence identical to r16/r19 -> absmax bit-identical.
// Block owns 16 voxels (grid 256 = 1/CU); acc[8]=x persistent; v in LDS;
// Delta in LDS chunk-major; 2 barriers/iter. LDS 64.5KB.
// ---------------------------------------------------------------------------
__global__ __launch_bounds__(256) void admm_fused4(
        const unsigned short* __restrict__ Whg,
        const unsigned short* __restrict__ Wlg,
        const unsigned short* __restrict__ D0h,
        const unsigned short* __restrict__ D0l,
        float* __restrict__ out) {
    __shared__ __align__(16) unsigned short DhL[8192];  // chunk-major, 16KB
    __shared__ __align__(16) unsigned short DlL[8192];
    __shared__ __align__(16) float vL[16 * 516];        // [vox][atom] pitch 516

    const int t = threadIdx.x;
    const int lane = t & 63, wv = t >> 6;   // 4 waves
    const int ln = lane & 15, kg = lane >> 4;
    const long vb = (long)blockIdx.x * 16;  // this block's voxel base

    // ---- preload Delta_0 (global linear [vox][atom] -> chunk-major LDS)
#pragma unroll
    for (int q = 0; q < 4; ++q) {
        int u = q * 256 + t;                // 1024 s8v units per buffer
        int vox = u >> 6, a8 = u & 63;      // atom group a = a8*8
        int ldsU = ((a8 >> 2) * 16 + vox) * 4 + (a8 & 3);
        long g = (vb + vox) * NATOMS + a8 * 8;
        *(s8v*)&DhL[ldsU * 8] = *(const s8v*)&D0h[g];
        *(s8v*)&DlL[ldsU * 8] = *(const s8v*)&D0l[g];
    }
    for (int i = t; i < 16 * 516; i += 256) vL[i] = 0.0f;   // v0 = 0
    __syncthreads();

    f32x4 acc[8] = {};                      // x = MFMA accumulator (32 VGPR)
    const int lanoff = ln * 32 + kg * 8;    // lane offset within a 1KB W block
    const int tb = wv * 8;                  // this wave's first tile

    s8v pAh[4], pAl[4], pBh[4], pBl[4];     // ping-pong W-frag buffers

#define LOADW(BUF, KC, GRP)                                                   \
    {                                                                         \
        _Pragma("unroll")                                                     \
        for (int q = 0; q < 4; ++q) {                                         \
            int off = ((tb + (GRP) * 4 + q) * 16 + (KC)) * 512 + lanoff;      \
            p##BUF##h[q] = *(const s8v*)&Whg[off];                            \
            p##BUF##l[q] = *(const s8v*)&Wlg[off];                            \
        }                                                                     \
    }
#define MFMAG(BUF, GRP, BH, BL)                                               \
    {                                                                         \
        _Pragma("unroll")                                                     \
        for (int q = 0; q < 4; ++q) {                                         \
            int mt = (GRP) * 4 + q;                                           \
            acc[mt] = __builtin_amdgcn_mfma_f32_16x16x32_bf16(p##BUF##h[q], BH, acc[mt], 0, 0, 0); \
            acc[mt] = __builtin_amdgcn_mfma_f32_16x16x32_bf16(p##BUF##h[q], BL, acc[mt], 0, 0, 0); \
            acc[mt] = __builtin_amdgcn_mfma_f32_16x16x32_bf16(p##BUF##l[q], BH, acc[mt], 0, 0, 0); \
        }                                                                     \
    }

#pragma unroll 1
    for (int it = 0; it < NITER; ++it) {
        // ---- GEMM: acc += W @ Delta  (C-in = x_{k-1}), prefetch-pipelined
        LOADW(A, 0, 0);
#pragma unroll 1
        for (int kc = 0; kc < 16; ++kc) {
            const int bidx = (((kc * 16 + ln) * 4) + kg) * 8;
            s8v bh = *(const s8v*)&DhL[bidx];
            s8v bl = *(const s8v*)&DlL[bidx];
            LOADW(B, kc, 1);                // group-1 loads fly over group-0 MFMAs
            MFMAG(A, 0, bh, bl);
            if (kc < 15) LOADW(A, kc + 1, 0);  // next-kc group-0 over group-1 MFMAs
            MFMAG(B, 1, bh, bl);
        }
        if (it == NITER - 1) break;         // acc holds x_30
        __syncthreads();                    // all waves done reading Delta
        // ---- epilogue: v' = x + min(v,0.1); Delta' = g(v')-g(v) -> LDS
#pragma unroll
        for (int mt = 0; mt < 8; ++mt) {
            int a0 = (wv * 8 + mt) * 16 + kg * 4;   // 4 consecutive atoms
            float* vp = &vL[ln * 516 + a0];
            f32x4 vo = *(const f32x4*)vp;
            f32x4 vn;
            s4v h4, l4;
#pragma unroll
            for (int j = 0; j < 4; ++j) {
                float x = acc[mt][j];
                float vnj = x + fminf(vo[j], 0.1f);
                float dlt = g_of(vnj) - g_of(vo[j]);
                vn[j] = vnj;
                unsigned short h = f2bf(dlt);
                h4[j] = (short)h;
                l4[j] = (short)f2bf(dlt - bf2f(h));
            }
            *(f32x4*)vp = vn;
            // chunk-major Delta store: a -> ((a>>5)*16+vox)*32 + ((a>>3)&3)*8 + (a&7)
            int lin = ((a0 >> 5) * 16 + ln) * 32 + ((a0 >> 3) & 3) * 8 + (a0 & 7);
            *(s4v*)&DhL[lin] = h4;
            *(s4v*)&DlL[lin] = l4;
        }
        __syncthreads();                    // Delta ready for next GEMM
    }
#undef LOADW
#undef MFMAG
    // ---- final: out[vox][atom] = x_30 (float4 direct)
#pragma unroll
    for (int mt = 0; mt < 8; ++mt) {
        int a0 = (wv * 8 + mt) * 16 + kg * 4;
        *(f32x4*)&out[(vb + ln) * NATOMS + a0] = acc[mt];
    }
}

// ---------------------------------------------------------------------------
extern "C" void kernel_launch(void* const* d_in, const int* in_sizes, int n_in,
                              void* d_out, int out_size, void* d_ws, size_t ws_size,
                              hipStream_t stream) {
    const float* Y = (const float*)d_in[0];   // [4096][256]
    const float* A = (const float*)d_in[1];   // [256][512]

    // ws layout (float units), lifetime-checked overlays (r3-r19 footprint).
    float* ws = (float*)d_ws;
    double* Gd  = (double*)(ws + 0);        // [0,131072)       dead after step 5
    float*  Gf  = ws + 131072;              // [131072,196608)  dead after sweep
    float*  X0f = ws + 196608;              // [196608,262144)  dead after step 4
    double* X1d = (double*)(ws + 262144);   // [262144,393216)  dead after step 6
    double* Pd  = (double*)(ws + 393216);   // [393216,524288)  dead after step 6
    double* X2d = (double*)(ws + 131072);   // overlays Gf+X0f (both dead)
    double* Hd  = (double*)(ws + 393216);   // [393216,655360) overlays Pd (dead)
    unsigned short* Whg = (unsigned short*)(ws + 0);        // overlays Gd (dead)
    unsigned short* Wlg = (unsigned short*)(ws + 131072);   // overlays X2d (dead after h)
    unsigned short* DAh = (unsigned short*)(ws + 2752512);  // Delta_0 hi
    unsigned short* DAl = (unsigned short*)(ws + 3801088);  // Delta_0 lo
    float* outp = (float*)d_out;

    g_kernel_d<<<256, 256, 0, stream>>>(A, Gd, Gf);                 // 1
    sweep_inverse<<<1, 1024, 0, stream>>>(Gf, X0f);                 // 2
    mm_gd<float><<<256, 256, 0, stream>>>(Gd, X0f, Pd);             // 3
    upd_newton<float><<<256, 256, 0, stream>>>(X0f, Pd, X1d);       // 4
    mm_gd<double><<<256, 256, 0, stream>>>(Gd, X1d, Pd);            // 5
    upd_newton<double><<<256, 256, 0, stream>>>(X1d, Pd, X2d);      // 6
    h_kernel_d<<<256, 256, 0, stream>>>(X2d, A, Hd);                // 7
    w_kernel_d<<<512, 256, 0, stream>>>(A, Hd, Whg, Wlg);           // 8
    aty_kernel<<<dim3(64, 8), 256, 0, stream>>>(A, Y, DAh, DAl);    // 9

    // 10: all 30 ADMM iterations, one persistent launch (256 blocks x 16 vox,
    //     256 thr / 4 waves, swizzled-W streaming + register prefetch)
    admm_fused4<<<256, 256, 0, stream>>>(Whg, Wlg, DAh, DAl, outp);
}

// Round 21
// 923.427 us; speedup vs baseline: 1.5353x; 1.0004x over previous
//
#include <hip/hip_runtime.h>

// Problem constants (from reference setup_inputs)
#define NVOX   4096   // B voxels
#define NMEAS  256    // M measurements
#define NATOMS 512    // K atoms
#define NITER  30

typedef __attribute__((ext_vector_type(8))) short s8v;   // 8 bf16 (4 VGPR) MFMA frag
typedef __attribute__((ext_vector_type(4))) short s4v;
typedef __attribute__((ext_vector_type(4))) float f32x4;

// bf16 round-to-nearest-even split helpers (no NaN/Inf in this problem)
__device__ __forceinline__ unsigned short f2bf(float x) {
    unsigned u = __builtin_bit_cast(unsigned, x);
    u += 0x7fff + ((u >> 16) & 1);
    return (unsigned short)(u >> 16);
}
__device__ __forceinline__ float bf2f(unsigned short b) {
    unsigned u = ((unsigned)b) << 16;
    return __builtin_bit_cast(float, u);
}
// g(v) = (z - u) collapsed through v = x + u :  relu(v-0.1) - min(v,0.1)
__device__ __forceinline__ float g_of(float v) {
    return fmaxf(v - 0.1f, 0.0f) - fminf(v, 0.1f);
}

// Swizzled streaming layout for W: element (p=row,q=col) lives at
// idx = ((((p>>4)*16 + (q>>5))*16 + (p&15))*4 + ((q>>3)&3))*8 + (q&7)
// i.e. block (tile=p>>4, kc=q>>5) of 512 shorts (1KB), lane (ln=p&15,
// kg=(q>>3)&3) at ln*32+kg*8. A wave's (tile,kc) read is ONE contiguous
// 1KB block; consecutive kc sequential -> channel-balanced L2 streams.
// (r19-proven: fused 940 -> 538us.)
__device__ __forceinline__ int wswz(int p, int q) {
    return ((((p >> 4) * 16 + (q >> 5)) * 16 + (p & 15)) * 4 + ((q >> 3) & 3)) * 8 + (q & 7);
}

// ---------------------------------------------------------------------------
// K0: G = I + A*A^T in fp64 (Gd) + fp32 copy (Gf) for the sweep
// ---------------------------------------------------------------------------
__global__ __launch_bounds__(256) void g_kernel_d(const float* __restrict__ A,
                                                  double* __restrict__ Gd,
                                                  float* __restrict__ Gf) {
    __shared__ float arow[NATOMS];
    int i = blockIdx.x;
    for (int k = threadIdx.x; k < NATOMS; k += 256) arow[k] = A[i * NATOMS + k];
    __syncthreads();
    int j = threadIdx.x;
    const float* aj = A + j * NATOMS;
    double s = (i == j) ? 1.0 : 0.0;
#pragma unroll 4
    for (int k = 0; k < NATOMS; ++k) s += (double)arow[k] * (double)aj[k];
    Gd[i * NMEAS + j] = s;
    Gf[i * NMEAS + j] = (float)s;
}

// ---------------------------------------------------------------------------
// K1: SPD inverse of Gf (256x256) via scalar symmetric SWEEP — r5-proven,
// 283us structural floor (r6/r7/r9/r14 blocked variants all spilled).
// sweep(all) = -G^{-1}; negate on store.
// ---------------------------------------------------------------------------
__global__ __launch_bounds__(1024) void sweep_inverse(const float* __restrict__ src,
                                                      float* __restrict__ dst) {
    __shared__ float s_dn[NMEAS];
    __shared__ float s_dt[NMEAS];
    int t = threadIdx.x;
    int rb = t & 31;
    int cb = t >> 5;
    float vals[8][8];
#pragma unroll
    for (int i = 0; i < 8; ++i) {
        const float* row = &src[(8 * rb + i) * NMEAS + 8 * cb];
        float4 a = *(const float4*)row;
        float4 b = *(const float4*)(row + 4);
        vals[i][0] = a.x; vals[i][1] = a.y; vals[i][2] = a.z; vals[i][3] = a.w;
        vals[i][4] = b.x; vals[i][5] = b.y; vals[i][6] = b.z; vals[i][7] = b.w;
    }
#pragma unroll 1
    for (int p = 0; p < NMEAS; ++p) {
        int pb = p >> 3, pi = p & 7;
        __syncthreads();
        if (cb == pb) {
#pragma unroll
            for (int i = 0; i < 8; ++i) {
                float v = vals[i][0];
#pragma unroll
                for (int j = 1; j < 8; ++j) if (pi == j) v = vals[i][j];
                s_dn[8 * rb + i] = v;
                s_dt[i * 32 + rb] = v;
            }
        }
        __syncthreads();
        float d   = s_dn[p];
        float inv = 1.0f / d;
        float rv[8], cv[8];
#pragma unroll
        for (int i = 0; i < 8; ++i) rv[i] = s_dt[i * 32 + rb];
#pragma unroll
        for (int j = 0; j < 8; ++j) cv[j] = s_dn[8 * cb + j] * inv;
#pragma unroll
        for (int i = 0; i < 8; ++i)
#pragma unroll
            for (int j = 0; j < 8; ++j) vals[i][j] -= rv[i] * cv[j];
        if (rb == pb) {
#pragma unroll
            for (int i = 0; i < 8; ++i) if (pi == i) {
#pragma unroll
                for (int j = 0; j < 8; ++j) vals[i][j] = cv[j];
            }
        }
        if (cb == pb) {
#pragma unroll
            for (int j = 0; j < 8; ++j) if (pi == j) {
#pragma unroll
                for (int i = 0; i < 8; ++i)
                    vals[i][j] = (rb == pb && pi == i) ? -inv : rv[i] * inv;
            }
        }
    }
#pragma unroll
    for (int i = 0; i < 8; ++i)
#pragma unroll
        for (int j = 0; j < 8; ++j)
            dst[(8 * rb + i) * NMEAS + 8 * cb + j] = -vals[i][j];
}

// ---------------------------------------------------------------------------
// fp64 Newton refinement:  P = Gd @ X ;  Xn = 2X - X @ P   (X input fp32/fp64)
// ---------------------------------------------------------------------------
template <typename TB>
__global__ __launch_bounds__(256) void mm_gd(const double* __restrict__ Gd,
                                             const TB* __restrict__ X,
                                             double* __restrict__ P) {
    __shared__ __align__(16) double row[NMEAS];
    int i = blockIdx.x;
    row[threadIdx.x] = Gd[i * NMEAS + threadIdx.x];
    __syncthreads();
    int j = threadIdx.x;
    double s = 0.0;
#pragma unroll 4
    for (int k = 0; k < NMEAS; ++k) s += row[k] * (double)X[k * NMEAS + j];
    P[i * NMEAS + j] = s;
}

template <typename TB>
__global__ __launch_bounds__(256) void upd_newton(const TB* __restrict__ X,
                                                  const double* __restrict__ P,
                                                  double* __restrict__ Xn) {
    __shared__ __align__(16) double row[NMEAS];
    int i = blockIdx.x;
    row[threadIdx.x] = (double)X[i * NMEAS + threadIdx.x];
    __syncthreads();
    int j = threadIdx.x;
    double s = 0.0;
#pragma unroll 4
    for (int k = 0; k < NMEAS; ++k) s += row[k] * P[k * NMEAS + j];
    Xn[i * NMEAS + j] = 2.0 * row[j] - s;
}

// ---------------------------------------------------------------------------
// K2: Hd = X2d @ A   (fp64 [256][256] @ fp32 [256][512] -> fp64 [256][512])
// ---------------------------------------------------------------------------
__global__ __launch_bounds__(256) void h_kernel_d(const double* __restrict__ Gi,
                                                  const float* __restrict__ A,
                                                  double* __restrict__ H) {
    __shared__ __align__(16) double grow[NMEAS];
    int i = blockIdx.x;
    grow[threadIdx.x] = Gi[i * NMEAS + threadIdx.x];
    __syncthreads();
    int k0 = threadIdx.x;
    double s0 = 0.0, s1 = 0.0;
#pragma unroll 4
    for (int j = 0; j < NMEAS; ++j) {
        double g = grow[j];
        s0 += g * (double)A[j * NATOMS + k0];
        s1 += g * (double)A[j * NATOMS + k0 + 256];
    }
    H[i * NATOMS + k0] = s0;
    H[i * NATOMS + k0 + 256] = s1;
}

// ---------------------------------------------------------------------------
// K3: W = I - A^T @ Hd  (fp64 accumulate), stored bf16 hi/lo in the
// SWIZZLED streaming layout (consumed only by the fused kernel).
// ---------------------------------------------------------------------------
__global__ __launch_bounds__(256) void w_kernel_d(const float* __restrict__ A,
                                                  const double* __restrict__ H,
                                                  unsigned short* __restrict__ Whg,
                                                  unsigned short* __restrict__ Wlg) {
    __shared__ __align__(16) double acol[NMEAS];
    int p = blockIdx.x;
    acol[threadIdx.x] = (double)A[threadIdx.x * NATOMS + p];
    __syncthreads();
    int q0 = threadIdx.x;
    double s0 = 0.0, s1 = 0.0;
#pragma unroll 4
    for (int m = 0; m < NMEAS; ++m) {
        double a = acol[m];
        s0 += a * H[m * NATOMS + q0];
        s1 += a * H[m * NATOMS + q0 + 256];
    }
    double w0 = ((p == q0)       ? 1.0 : 0.0) - s0;
    double w1 = ((p == q0 + 256) ? 1.0 : 0.0) - s1;
    unsigned short h0 = f2bf((float)w0), h1 = f2bf((float)w1);
    int i0 = wswz(p, q0), i1 = wswz(p, q0 + 256);
    Whg[i0] = h0;
    Wlg[i0] = f2bf((float)(w0 - (double)bf2f(h0)));
    Whg[i1] = h1;
    Wlg[i1] = f2bf((float)(w1 - (double)bf2f(h1)));
}

// ---------------------------------------------------------------------------
// K4: Delta0 = AtY (= t_1, since t_0 = 0), stored split bf16 hi/lo,
//     TRANSPOSED to [4096 voxels][512 atoms].
// AtY[k][b] = sum_m A[m][k] * Y[b][m]
// ---------------------------------------------------------------------------
__global__ __launch_bounds__(256) void aty_kernel(const float* __restrict__ A,
                                                  const float* __restrict__ Y,
                                                  unsigned short* __restrict__ Dh0,
                                                  unsigned short* __restrict__ Dl0) {
    __shared__ __align__(16) float At[64][65];
    __shared__ __align__(16) float Yt[64][65];
    int b0 = blockIdx.x * 64, k0 = blockIdx.y * 64;
    int t = threadIdx.x, tx = t & 15, ty = t >> 4;
    float acc[4][4] = {};
    for (int m0 = 0; m0 < NMEAS; m0 += 64) {
        __syncthreads();
        {
            int kk = t & 63, mr = t >> 6;
#pragma unroll
            for (int p = 0; p < 16; ++p)
                At[mr + 4 * p][kk] = A[(m0 + mr + 4 * p) * NATOMS + k0 + kk];
            int mm = t & 63, br = t >> 6;
#pragma unroll
            for (int p = 0; p < 16; ++p)
                Yt[mm][br + 4 * p] = Y[(b0 + br + 4 * p) * NMEAS + m0 + mm];
        }
        __syncthreads();
#pragma unroll 4
        for (int m = 0; m < 64; ++m) {
            float av[4], yv[4];
#pragma unroll
            for (int i = 0; i < 4; ++i) av[i] = At[m][ty * 4 + i];
#pragma unroll
            for (int j = 0; j < 4; ++j) yv[j] = Yt[m][tx * 4 + j];
#pragma unroll
            for (int i = 0; i < 4; ++i)
#pragma unroll
                for (int j = 0; j < 4; ++j) acc[i][j] += av[i] * yv[j];
        }
    }
#pragma unroll
    for (int j = 0; j < 4; ++j) {
        int b = b0 + tx * 4 + j;
        s4v h4, l4;
#pragma unroll
        for (int i = 0; i < 4; ++i) {
            float f = acc[i][j];
            unsigned short h = f2bf(f);
            h4[i] = (short)h;
            l4[i] = (short)f2bf(f - bf2f(h));
        }
        *(s4v*)&Dh0[(long)b * NATOMS + k0 + ty * 4] = h4;
        *(s4v*)&Dl0[(long)b * NATOMS + k0 + ty * 4] = l4;
    }
}

// ---------------------------------------------------------------------------
// K5: PERSISTENT fused ADMM v5 — swizzled-W + FULL next-kc double buffering.
// r20 (v4) showed shallow prefetch stalls: each 8-load group had only ~58cyc
// of MFMA cover vs ~200cyc L2 latency. v5 prefetches BOTH groups of kc+1
// (16 loads in flight) before any of kc's 48 MFMAs (~233cyc cover >= L2
// latency). Implemented as 2-kc unrolled ping-pong over named buffer sets
// b*/c* (compile-time indices, rule #20). Register demand ~175 (buffers 128
// + acc 32 + misc); 256-thr kernels have been granted 164 (m97), and
// __launch_bounds__(256,1) legalizes 512. Per-acc MFMA order (kc ascending,
// group0 then group1) identical to r19/r20 -> absmax bit-identical.
// Block owns 16 voxels (grid 256 = 1/CU); acc[8]=x persistent; v in LDS;
// Delta in LDS chunk-major; 2 barriers/iter. LDS 64.5KB.
// ---------------------------------------------------------------------------
__global__ __launch_bounds__(256, 1) void admm_fused5(
        const unsigned short* __restrict__ Whg,
        const unsigned short* __restrict__ Wlg,
        const unsigned short* __restrict__ D0h,
        const unsigned short* __restrict__ D0l,
        float* __restrict__ out) {
    __shared__ __align__(16) unsigned short DhL[8192];  // chunk-major, 16KB
    __shared__ __align__(16) unsigned short DlL[8192];
    __shared__ __align__(16) float vL[16 * 516];        // [vox][atom] pitch 516

    const int t = threadIdx.x;
    const int lane = t & 63, wv = t >> 6;   // 4 waves
    const int ln = lane & 15, kg = lane >> 4;
    const long vb = (long)blockIdx.x * 16;  // this block's voxel base

    // ---- preload Delta_0 (global linear [vox][atom] -> chunk-major LDS)
#pragma unroll
    for (int q = 0; q < 4; ++q) {
        int u = q * 256 + t;                // 1024 s8v units per buffer
        int vox = u >> 6, a8 = u & 63;      // atom group a = a8*8
        int ldsU = ((a8 >> 2) * 16 + vox) * 4 + (a8 & 3);
        long g = (vb + vox) * NATOMS + a8 * 8;
        *(s8v*)&DhL[ldsU * 8] = *(const s8v*)&D0h[g];
        *(s8v*)&DlL[ldsU * 8] = *(const s8v*)&D0l[g];
    }
    for (int i = t; i < 16 * 516; i += 256) vL[i] = 0.0f;   // v0 = 0
    __syncthreads();

    f32x4 acc[8] = {};                      // x = MFMA accumulator (32 VGPR)
    const int lanoff = ln * 32 + kg * 8;    // lane offset within a 1KB W block
    const int tb = wv * 8;                  // this wave's first tile

    // double-buffer sets: b* = even-kc, c* = odd-kc (named, compile-time)
    s8v b0h[4], b0l[4], b1h[4], b1l[4];
    s8v c0h[4], c0l[4], c1h[4], c1l[4];

#define LOADW(P, KC, GRP)                                                     \
    {                                                                         \
        _Pragma("unroll")                                                     \
        for (int q = 0; q < 4; ++q) {                                         \
            int off = ((tb + (GRP) * 4 + q) * 16 + (KC)) * 512 + lanoff;      \
            P##h[q] = *(const s8v*)&Whg[off];                                 \
            P##l[q] = *(const s8v*)&Wlg[off];                                 \
        }                                                                     \
    }
#define MFMAG(P, GRP, BH, BL)                                                 \
    {                                                                         \
        _Pragma("unroll")                                                     \
        for (int q = 0; q < 4; ++q) {                                         \
            int mt = (GRP) * 4 + q;                                           \
            acc[mt] = __builtin_amdgcn_mfma_f32_16x16x32_bf16(P##h[q], BH, acc[mt], 0, 0, 0); \
            acc[mt] = __builtin_amdgcn_mfma_f32_16x16x32_bf16(P##h[q], BL, acc[mt], 0, 0, 0); \
            acc[mt] = __builtin_amdgcn_mfma_f32_16x16x32_bf16(P##l[q], BH, acc[mt], 0, 0, 0); \
        }                                                                     \
    }

#pragma unroll 1
    for (int it = 0; it < NITER; ++it) {
        // ---- GEMM: acc += W @ Delta  (C-in = x_{k-1}), deep-pipelined
        LOADW(b0, 0, 0); LOADW(b1, 0, 1);
#pragma unroll 1
        for (int kc2 = 0; kc2 < 16; kc2 += 2) {
            {   // even kc2: consume b*, prefetch c* for kc2+1
                const int bidx = (((kc2 * 16 + ln) * 4) + kg) * 8;
                s8v bh = *(const s8v*)&DhL[bidx];
                s8v bl = *(const s8v*)&DlL[bidx];
                LOADW(c0, kc2 + 1, 0); LOADW(c1, kc2 + 1, 1);
                MFMAG(b0, 0, bh, bl);
                MFMAG(b1, 1, bh, bl);
            }
            {   // odd kc2+1: consume c*, prefetch b* for kc2+2
                const int bidx = ((((kc2 + 1) * 16 + ln) * 4) + kg) * 8;
                s8v bh = *(const s8v*)&DhL[bidx];
                s8v bl = *(const s8v*)&DlL[bidx];
                if (kc2 + 2 < 16) { LOADW(b0, kc2 + 2, 0); LOADW(b1, kc2 + 2, 1); }
                MFMAG(c0, 0, bh, bl);
                MFMAG(c1, 1, bh, bl);
            }
        }
        if (it == NITER - 1) break;         // acc holds x_30
        __syncthreads();                    // all waves done reading Delta
        // ---- epilogue: v' = x + min(v,0.1); Delta' = g(v')-g(v) -> LDS
#pragma unroll
        for (int mt = 0; mt < 8; ++mt) {
            int a0 = (wv * 8 + mt) * 16 + kg * 4;   // 4 consecutive atoms
            float* vp = &vL[ln * 516 + a0];
            f32x4 vo = *(const f32x4*)vp;
            f32x4 vn;
            s4v h4, l4;
#pragma unroll
            for (int j = 0; j < 4; ++j) {
                float x = acc[mt][j];
                float vnj = x + fminf(vo[j], 0.1f);
                float dlt = g_of(vnj) - g_of(vo[j]);
                vn[j] = vnj;
                unsigned short h = f2bf(dlt);
                h4[j] = (short)h;
                l4[j] = (short)f2bf(dlt - bf2f(h));
            }
            *(f32x4*)vp = vn;
            // chunk-major Delta store: a -> ((a>>5)*16+vox)*32 + ((a>>3)&3)*8 + (a&7)
            int lin = ((a0 >> 5) * 16 + ln) * 32 + ((a0 >> 3) & 3) * 8 + (a0 & 7);
            *(s4v*)&DhL[lin] = h4;
            *(s4v*)&DlL[lin] = l4;
        }
        __syncthreads();                    // Delta ready for next GEMM
    }
#undef LOADW
#undef MFMAG
    // ---- final: out[vox][atom] = x_30 (float4 direct)
#pragma unroll
    for (int mt = 0; mt < 8; ++mt) {
        int a0 = (wv * 8 + mt) * 16 + kg * 4;
        *(f32x4*)&out[(vb + ln) * NATOMS + a0] = acc[mt];
    }
}

// ---------------------------------------------------------------------------
extern "C" void kernel_launch(void* const* d_in, const int* in_sizes, int n_in,
                              void* d_out, int out_size, void* d_ws, size_t ws_size,
                              hipStream_t stream) {
    const float* Y = (const float*)d_in[0];   // [4096][256]
    const float* A = (const float*)d_in[1];   // [256][512]

    // ws layout (float units), lifetime-checked overlays (r3-r20 footprint).
    float* ws = (float*)d_ws;
    double* Gd  = (double*)(ws + 0);        // [0,131072)       dead after step 5
    float*  Gf  = ws + 131072;              // [131072,196608)  dead after sweep
    float*  X0f = ws + 196608;              // [196608,262144)  dead after step 4
    double* X1d = (double*)(ws + 262144);   // [262144,393216)  dead after step 6
    double* Pd  = (double*)(ws + 393216);   // [393216,524288)  dead after step 6
    double* X2d = (double*)(ws + 131072);   // overlays Gf+X0f (both dead)
    double* Hd  = (double*)(ws + 393216);   // [393216,655360) overlays Pd (dead)
    unsigned short* Whg = (unsigned short*)(ws + 0);        // overlays Gd (dead)
    unsigned short* Wlg = (unsigned short*)(ws + 131072);   // overlays X2d (dead after h)
    unsigned short* DAh = (unsigned short*)(ws + 2752512);  // Delta_0 hi
    unsigned short* DAl = (unsigned short*)(ws + 3801088);  // Delta_0 lo
    float* outp = (float*)d_out;

    g_kernel_d<<<256, 256, 0, stream>>>(A, Gd, Gf);                 // 1
    sweep_inverse<<<1, 1024, 0, stream>>>(Gf, X0f);                 // 2
    mm_gd<float><<<256, 256, 0, stream>>>(Gd, X0f, Pd);             // 3
    upd_newton<float><<<256, 256, 0, stream>>>(X0f, Pd, X1d);       // 4
    mm_gd<double><<<256, 256, 0, stream>>>(Gd, X1d, Pd);            // 5
    upd_newton<double><<<256, 256, 0, stream>>>(X1d, Pd, X2d);      // 6
    h_kernel_d<<<256, 256, 0, stream>>>(X2d, A, Hd);                // 7
    w_kernel_d<<<512, 256, 0, stream>>>(A, Hd, Whg, Wlg);           // 8
    aty_kernel<<<dim3(64, 8), 256, 0, stream>>>(A, Y, DAh, DAl);    // 9

    // 10: all 30 ADMM iterations, one persistent launch (256 blocks x 16 vox,
    //     256 thr / 4 waves, swizzled-W + full next-kc double buffering)
    admm_fused5<<<256, 256, 0, stream>>>(Whg, Wlg, DAh, DAl, outp);
}

// Round 22
// 913.366 us; speedup vs baseline: 1.5522x; 1.0110x over previous
//
#include <hip/hip_runtime.h>

// Problem constants (from reference setup_inputs)
#define NVOX   4096   // B voxels
#define NMEAS  256    // M measurements
#define NATOMS 512    // K atoms
#define NITER  30

typedef __attribute__((ext_vector_type(8))) short s8v;   // 8 bf16 (4 VGPR) MFMA frag
typedef __attribute__((ext_vector_type(4))) short s4v;
typedef __attribute__((ext_vector_type(4))) float f32x4;

// bf16 round-to-nearest-even split helpers (no NaN/Inf in this problem)
__device__ __forceinline__ unsigned short f2bf(float x) {
    unsigned u = __builtin_bit_cast(unsigned, x);
    u += 0x7fff + ((u >> 16) & 1);
    return (unsigned short)(u >> 16);
}
__device__ __forceinline__ float bf2f(unsigned short b) {
    unsigned u = ((unsigned)b) << 16;
    return __builtin_bit_cast(float, u);
}
// g(v) = (z - u) collapsed through v = x + u :  relu(v-0.1) - min(v,0.1)
__device__ __forceinline__ float g_of(float v) {
    return fmaxf(v - 0.1f, 0.0f) - fminf(v, 0.1f);
}

// Swizzled streaming layout for W: element (p=row,q=col) lives at
// idx = ((((p>>4)*16 + (q>>5))*16 + (p&15))*4 + ((q>>3)&3))*8 + (q&7)
// i.e. block (tile=p>>4, kc=q>>5) of 512 shorts (1KB), lane (ln=p&15,
// kg=(q>>3)&3) at ln*32+kg*8. (r19-proven: fused 940 -> 538us.)
__device__ __forceinline__ int wswz(int p, int q) {
    return ((((p >> 4) * 16 + (q >> 5)) * 16 + (p & 15)) * 4 + ((q >> 3) & 3)) * 8 + (q & 7);
}

// ---------------------------------------------------------------------------
// K0: G = I + A*A^T in fp64 (Gd) + fp32 copy (Gf) for the sweep
// ---------------------------------------------------------------------------
__global__ __launch_bounds__(256) void g_kernel_d(const float* __restrict__ A,
                                                  double* __restrict__ Gd,
                                                  float* __restrict__ Gf) {
    __shared__ float arow[NATOMS];
    int i = blockIdx.x;
    for (int k = threadIdx.x; k < NATOMS; k += 256) arow[k] = A[i * NATOMS + k];
    __syncthreads();
    int j = threadIdx.x;
    const float* aj = A + j * NATOMS;
    double s = (i == j) ? 1.0 : 0.0;
#pragma unroll 4
    for (int k = 0; k < NATOMS; ++k) s += (double)arow[k] * (double)aj[k];
    Gd[i * NMEAS + j] = s;
    Gf[i * NMEAS + j] = (float)s;
}

// ---------------------------------------------------------------------------
// K1: SPD inverse of Gf (256x256) via scalar symmetric SWEEP — r5-proven,
// 283us structural floor (r6/r7/r9/r14 blocked variants all spilled).
// sweep(all) = -G^{-1}; negate on store.
// ---------------------------------------------------------------------------
__global__ __launch_bounds__(1024) void sweep_inverse(const float* __restrict__ src,
                                                      float* __restrict__ dst) {
    __shared__ float s_dn[NMEAS];
    __shared__ float s_dt[NMEAS];
    int t = threadIdx.x;
    int rb = t & 31;
    int cb = t >> 5;
    float vals[8][8];
#pragma unroll
    for (int i = 0; i < 8; ++i) {
        const float* row = &src[(8 * rb + i) * NMEAS + 8 * cb];
        float4 a = *(const float4*)row;
        float4 b = *(const float4*)(row + 4);
        vals[i][0] = a.x; vals[i][1] = a.y; vals[i][2] = a.z; vals[i][3] = a.w;
        vals[i][4] = b.x; vals[i][5] = b.y; vals[i][6] = b.z; vals[i][7] = b.w;
    }
#pragma unroll 1
    for (int p = 0; p < NMEAS; ++p) {
        int pb = p >> 3, pi = p & 7;
        __syncthreads();
        if (cb == pb) {
#pragma unroll
            for (int i = 0; i < 8; ++i) {
                float v = vals[i][0];
#pragma unroll
                for (int j = 1; j < 8; ++j) if (pi == j) v = vals[i][j];
                s_dn[8 * rb + i] = v;
                s_dt[i * 32 + rb] = v;
            }
        }
        __syncthreads();
        float d   = s_dn[p];
        float inv = 1.0f / d;
        float rv[8], cv[8];
#pragma unroll
        for (int i = 0; i < 8; ++i) rv[i] = s_dt[i * 32 + rb];
#pragma unroll
        for (int j = 0; j < 8; ++j) cv[j] = s_dn[8 * cb + j] * inv;
#pragma unroll
        for (int i = 0; i < 8; ++i)
#pragma unroll
            for (int j = 0; j < 8; ++j) vals[i][j] -= rv[i] * cv[j];
        if (rb == pb) {
#pragma unroll
            for (int i = 0; i < 8; ++i) if (pi == i) {
#pragma unroll
                for (int j = 0; j < 8; ++j) vals[i][j] = cv[j];
            }
        }
        if (cb == pb) {
#pragma unroll
            for (int j = 0; j < 8; ++j) if (pi == j) {
#pragma unroll
                for (int i = 0; i < 8; ++i)
                    vals[i][j] = (rb == pb && pi == i) ? -inv : rv[i] * inv;
            }
        }
    }
#pragma unroll
    for (int i = 0; i < 8; ++i)
#pragma unroll
        for (int j = 0; j < 8; ++j)
            dst[(8 * rb + i) * NMEAS + 8 * cb + j] = -vals[i][j];
}

// ---------------------------------------------------------------------------
// fp64 Newton refinement:  P = Gd @ X ;  Xn = 2X - X @ P   (X input fp32/fp64)
// ---------------------------------------------------------------------------
template <typename TB>
__global__ __launch_bounds__(256) void mm_gd(const double* __restrict__ Gd,
                                             const TB* __restrict__ X,
                                             double* __restrict__ P) {
    __shared__ __align__(16) double row[NMEAS];
    int i = blockIdx.x;
    row[threadIdx.x] = Gd[i * NMEAS + threadIdx.x];
    __syncthreads();
    int j = threadIdx.x;
    double s = 0.0;
#pragma unroll 4
    for (int k = 0; k < NMEAS; ++k) s += row[k] * (double)X[k * NMEAS + j];
    P[i * NMEAS + j] = s;
}

template <typename TB>
__global__ __launch_bounds__(256) void upd_newton(const TB* __restrict__ X,
                                                  const double* __restrict__ P,
                                                  double* __restrict__ Xn) {
    __shared__ __align__(16) double row[NMEAS];
    int i = blockIdx.x;
    row[threadIdx.x] = (double)X[i * NMEAS + threadIdx.x];
    __syncthreads();
    int j = threadIdx.x;
    double s = 0.0;
#pragma unroll 4
    for (int k = 0; k < NMEAS; ++k) s += row[k] * P[k * NMEAS + j];
    Xn[i * NMEAS + j] = 2.0 * row[j] - s;
}

// ---------------------------------------------------------------------------
// K2: Hd = X2d @ A   (fp64 [256][256] @ fp32 [256][512] -> fp64 [256][512])
// ---------------------------------------------------------------------------
__global__ __launch_bounds__(256) void h_kernel_d(const double* __restrict__ Gi,
                                                  const float* __restrict__ A,
                                                  double* __restrict__ H) {
    __shared__ __align__(16) double grow[NMEAS];
    int i = blockIdx.x;
    grow[threadIdx.x] = Gi[i * NMEAS + threadIdx.x];
    __syncthreads();
    int k0 = threadIdx.x;
    double s0 = 0.0, s1 = 0.0;
#pragma unroll 4
    for (int j = 0; j < NMEAS; ++j) {
        double g = grow[j];
        s0 += g * (double)A[j * NATOMS + k0];
        s1 += g * (double)A[j * NATOMS + k0 + 256];
    }
    H[i * NATOMS + k0] = s0;
    H[i * NATOMS + k0 + 256] = s1;
}

// ---------------------------------------------------------------------------
// K3: W = I - A^T @ Hd  (fp64 accumulate), stored bf16 hi/lo in the
// SWIZZLED streaming layout (consumed only by the fused kernel).
// ---------------------------------------------------------------------------
__global__ __launch_bounds__(256) void w_kernel_d(const float* __restrict__ A,
                                                  const double* __restrict__ H,
                                                  unsigned short* __restrict__ Whg,
                                                  unsigned short* __restrict__ Wlg) {
    __shared__ __align__(16) double acol[NMEAS];
    int p = blockIdx.x;
    acol[threadIdx.x] = (double)A[threadIdx.x * NATOMS + p];
    __syncthreads();
    int q0 = threadIdx.x;
    double s0 = 0.0, s1 = 0.0;
#pragma unroll 4
    for (int m = 0; m < NMEAS; ++m) {
        double a = acol[m];
        s0 += a * H[m * NATOMS + q0];
        s1 += a * H[m * NATOMS + q0 + 256];
    }
    double w0 = ((p == q0)       ? 1.0 : 0.0) - s0;
    double w1 = ((p == q0 + 256) ? 1.0 : 0.0) - s1;
    unsigned short h0 = f2bf((float)w0), h1 = f2bf((float)w1);
    int i0 = wswz(p, q0), i1 = wswz(p, q0 + 256);
    Whg[i0] = h0;
    Wlg[i0] = f2bf((float)(w0 - (double)bf2f(h0)));
    Whg[i1] = h1;
    Wlg[i1] = f2bf((float)(w1 - (double)bf2f(h1)));
}

// ---------------------------------------------------------------------------
// K4: Delta0 = AtY (= t_1, since t_0 = 0), stored split bf16 hi/lo,
//     TRANSPOSED to [4096 voxels][512 atoms].
// AtY[k][b] = sum_m A[m][k] * Y[b][m]
// ---------------------------------------------------------------------------
__global__ __launch_bounds__(256) void aty_kernel(const float* __restrict__ A,
                                                  const float* __restrict__ Y,
                                                  unsigned short* __restrict__ Dh0,
                                                  unsigned short* __restrict__ Dl0) {
    __shared__ __align__(16) float At[64][65];
    __shared__ __align__(16) float Yt[64][65];
    int b0 = blockIdx.x * 64, k0 = blockIdx.y * 64;
    int t = threadIdx.x, tx = t & 15, ty = t >> 4;
    float acc[4][4] = {};
    for (int m0 = 0; m0 < NMEAS; m0 += 64) {
        __syncthreads();
        {
            int kk = t & 63, mr = t >> 6;
#pragma unroll
            for (int p = 0; p < 16; ++p)
                At[mr + 4 * p][kk] = A[(m0 + mr + 4 * p) * NATOMS + k0 + kk];
            int mm = t & 63, br = t >> 6;
#pragma unroll
            for (int p = 0; p < 16; ++p)
                Yt[mm][br + 4 * p] = Y[(b0 + br + 4 * p) * NMEAS + m0 + mm];
        }
        __syncthreads();
#pragma unroll 4
        for (int m = 0; m < 64; ++m) {
            float av[4], yv[4];
#pragma unroll
            for (int i = 0; i < 4; ++i) av[i] = At[m][ty * 4 + i];
#pragma unroll
            for (int j = 0; j < 4; ++j) yv[j] = Yt[m][tx * 4 + j];
#pragma unroll
            for (int i = 0; i < 4; ++i)
#pragma unroll
                for (int j = 0; j < 4; ++j) acc[i][j] += av[i] * yv[j];
        }
    }
#pragma unroll
    for (int j = 0; j < 4; ++j) {
        int b = b0 + tx * 4 + j;
        s4v h4, l4;
#pragma unroll
        for (int i = 0; i < 4; ++i) {
            float f = acc[i][j];
            unsigned short h = f2bf(f);
            h4[i] = (short)h;
            l4[i] = (short)f2bf(f - bf2f(h));
        }
        *(s4v*)&Dh0[(long)b * NATOMS + k0 + ty * 4] = h4;
        *(s4v*)&Dl0[(long)b * NATOMS + k0 + ty * 4] = l4;
    }
}

// ---------------------------------------------------------------------------
// K5: PERSISTENT fused ADMM v6 — v5 + PER-BLOCK kc ROTATION.
// r19/r20/r21 evidence: three schedules (2 waves/SIMD no-prefetch, shallow
// prefetch, deep prefetch at VGPR=172 no-spill) ALL land at ~17.5us/iter =
// ~24 B/cyc/CU — schedule-invariant => not latency. Surviving theory:
// same-address L2 CAMPING — all 32 CUs of an XCD stream identical W
// addresses in near-lockstep, piling onto the same L2 banks each cycle.
// v6: block-dependent kc start rot=((blockIdx>>3)*11)&15 (XCD-mates get all
// 16 phases uniformly; 11 coprime 16) decorrelates the streams. A/B kc stay
// paired — pure summation reorder (absmax may shift ~1ulp; margin 5.5x).
// Everything else identical to v5 (proven).
// ---------------------------------------------------------------------------
__global__ __launch_bounds__(256, 1) void admm_fused6(
        const unsigned short* __restrict__ Whg,
        const unsigned short* __restrict__ Wlg,
        const unsigned short* __restrict__ D0h,
        const unsigned short* __restrict__ D0l,
        float* __restrict__ out) {
    __shared__ __align__(16) unsigned short DhL[8192];  // chunk-major, 16KB
    __shared__ __align__(16) unsigned short DlL[8192];
    __shared__ __align__(16) float vL[16 * 516];        // [vox][atom] pitch 516

    const int t = threadIdx.x;
    const int lane = t & 63, wv = t >> 6;   // 4 waves
    const int ln = lane & 15, kg = lane >> 4;
    const long vb = (long)blockIdx.x * 16;  // this block's voxel base
    const int rot = ((blockIdx.x >> 3) * 11) & 15;   // per-block kc phase

    // ---- preload Delta_0 (global linear [vox][atom] -> chunk-major LDS)
#pragma unroll
    for (int q = 0; q < 4; ++q) {
        int u = q * 256 + t;                // 1024 s8v units per buffer
        int vox = u >> 6, a8 = u & 63;      // atom group a = a8*8
        int ldsU = ((a8 >> 2) * 16 + vox) * 4 + (a8 & 3);
        long g = (vb + vox) * NATOMS + a8 * 8;
        *(s8v*)&DhL[ldsU * 8] = *(const s8v*)&D0h[g];
        *(s8v*)&DlL[ldsU * 8] = *(const s8v*)&D0l[g];
    }
    for (int i = t; i < 16 * 516; i += 256) vL[i] = 0.0f;   // v0 = 0
    __syncthreads();

    f32x4 acc[8] = {};                      // x = MFMA accumulator (32 VGPR)
    const int lanoff = ln * 32 + kg * 8;    // lane offset within a 1KB W block
    const int tb = wv * 8;                  // this wave's first tile

    // double-buffer sets: b* = even phase, c* = odd phase (named, rule #20)
    s8v b0h[4], b0l[4], b1h[4], b1l[4];
    s8v c0h[4], c0l[4], c1h[4], c1l[4];

#define LOADW(P, KC, GRP)                                                     \
    {                                                                         \
        _Pragma("unroll")                                                     \
        for (int q = 0; q < 4; ++q) {                                         \
            int off = ((tb + (GRP) * 4 + q) * 16 + (KC)) * 512 + lanoff;      \
            P##h[q] = *(const s8v*)&Whg[off];                                 \
            P##l[q] = *(const s8v*)&Wlg[off];                                 \
        }                                                                     \
    }
#define MFMAG(P, GRP, BH, BL)                                                 \
    {                                                                         \
        _Pragma("unroll")                                                     \
        for (int q = 0; q < 4; ++q) {                                         \
            int mt = (GRP) * 4 + q;                                           \
            acc[mt] = __builtin_amdgcn_mfma_f32_16x16x32_bf16(P##h[q], BH, acc[mt], 0, 0, 0); \
            acc[mt] = __builtin_amdgcn_mfma_f32_16x16x32_bf16(P##h[q], BL, acc[mt], 0, 0, 0); \
            acc[mt] = __builtin_amdgcn_mfma_f32_16x16x32_bf16(P##l[q], BH, acc[mt], 0, 0, 0); \
        }                                                                     \
    }

#pragma unroll 1
    for (int it = 0; it < NITER; ++it) {
        // ---- GEMM: acc += W @ Delta  (C-in = x_{k-1}), deep-pipelined,
        //      per-block rotated kc order (camping decorrelation)
        LOADW(b0, rot, 0); LOADW(b1, rot, 1);
#pragma unroll 1
        for (int i2 = 0; i2 < 16; i2 += 2) {
            const int kcA = (i2 + rot) & 15;
            const int kcB = (i2 + 1 + rot) & 15;
            const int kcN = (i2 + 2 + rot) & 15;
            {   // even phase: consume b* (kcA), prefetch c* (kcB)
                const int bidx = (((kcA * 16 + ln) * 4) + kg) * 8;
                s8v bh = *(const s8v*)&DhL[bidx];
                s8v bl = *(const s8v*)&DlL[bidx];
                LOADW(c0, kcB, 0); LOADW(c1, kcB, 1);
                MFMAG(b0, 0, bh, bl);
                MFMAG(b1, 1, bh, bl);
            }
            {   // odd phase: consume c* (kcB), prefetch b* (kcN)
                const int bidx = (((kcB * 16 + ln) * 4) + kg) * 8;
                s8v bh = *(const s8v*)&DhL[bidx];
                s8v bl = *(const s8v*)&DlL[bidx];
                if (i2 + 2 < 16) { LOADW(b0, kcN, 0); LOADW(b1, kcN, 1); }
                MFMAG(c0, 0, bh, bl);
                MFMAG(c1, 1, bh, bl);
            }
        }
        if (it == NITER - 1) break;         // acc holds x_30
        __syncthreads();                    // all waves done reading Delta
        // ---- epilogue: v' = x + min(v,0.1); Delta' = g(v')-g(v) -> LDS
#pragma unroll
        for (int mt = 0; mt < 8; ++mt) {
            int a0 = (wv * 8 + mt) * 16 + kg * 4;   // 4 consecutive atoms
            float* vp = &vL[ln * 516 + a0];
            f32x4 vo = *(const f32x4*)vp;
            f32x4 vn;
            s4v h4, l4;
#pragma unroll
            for (int j = 0; j < 4; ++j) {
                float x = acc[mt][j];
                float vnj = x + fminf(vo[j], 0.1f);
                float dlt = g_of(vnj) - g_of(vo[j]);
                vn[j] = vnj;
                unsigned short h = f2bf(dlt);
                h4[j] = (short)h;
                l4[j] = (short)f2bf(dlt - bf2f(h));
            }
            *(f32x4*)vp = vn;
            // chunk-major Delta store: a -> ((a>>5)*16+vox)*32 + ((a>>3)&3)*8 + (a&7)
            int lin = ((a0 >> 5) * 16 + ln) * 32 + ((a0 >> 3) & 3) * 8 + (a0 & 7);
            *(s4v*)&DhL[lin] = h4;
            *(s4v*)&DlL[lin] = l4;
        }
        __syncthreads();                    // Delta ready for next GEMM
    }
#undef LOADW
#undef MFMAG
    // ---- final: out[vox][atom] = x_30 (float4 direct)
#pragma unroll
    for (int mt = 0; mt < 8; ++mt) {
        int a0 = (wv * 8 + mt) * 16 + kg * 4;
        *(f32x4*)&out[(vb + ln) * NATOMS + a0] = acc[mt];
    }
}

// ---------------------------------------------------------------------------
extern "C" void kernel_launch(void* const* d_in, const int* in_sizes, int n_in,
                              void* d_out, int out_size, void* d_ws, size_t ws_size,
                              hipStream_t stream) {
    const float* Y = (const float*)d_in[0];   // [4096][256]
    const float* A = (const float*)d_in[1];   // [256][512]

    // ws layout (float units), lifetime-checked overlays (r3-r21 footprint).
    float* ws = (float*)d_ws;
    double* Gd  = (double*)(ws + 0);        // [0,131072)       dead after step 5
    float*  Gf  = ws + 131072;              // [131072,196608)  dead after sweep
    float*  X0f = ws + 196608;              // [196608,262144)  dead after step 4
    double* X1d = (double*)(ws + 262144);   // [262144,393216)  dead after step 6
    double* Pd  = (double*)(ws + 393216);   // [393216,524288)  dead after step 6
    double* X2d = (double*)(ws + 131072);   // overlays Gf+X0f (both dead)
    double* Hd  = (double*)(ws + 393216);   // [393216,655360) overlays Pd (dead)
    unsigned short* Whg = (unsigned short*)(ws + 0);        // overlays Gd (dead)
    unsigned short* Wlg = (unsigned short*)(ws + 131072);   // overlays X2d (dead after h)
    unsigned short* DAh = (unsigned short*)(ws + 2752512);  // Delta_0 hi
    unsigned short* DAl = (unsigned short*)(ws + 3801088);  // Delta_0 lo
    float* outp = (float*)d_out;

    g_kernel_d<<<256, 256, 0, stream>>>(A, Gd, Gf);                 // 1
    sweep_inverse<<<1, 1024, 0, stream>>>(Gf, X0f);                 // 2
    mm_gd<float><<<256, 256, 0, stream>>>(Gd, X0f, Pd);             // 3
    upd_newton<float><<<256, 256, 0, stream>>>(X0f, Pd, X1d);       // 4
    mm_gd<double><<<256, 256, 0, stream>>>(Gd, X1d, Pd);            // 5
    upd_newton<double><<<256, 256, 0, stream>>>(X1d, Pd, X2d);      // 6
    h_kernel_d<<<256, 256, 0, stream>>>(X2d, A, Hd);                // 7
    w_kernel_d<<<512, 256, 0, stream>>>(A, Hd, Whg, Wlg);           // 8
    aty_kernel<<<dim3(64, 8), 256, 0, stream>>>(A, Y, DAh, DAl);    // 9

    // 10: all 30 ADMM iterations, one persistent launch (256 blocks x 16 vox,
    //     256 thr / 4 waves, swizzled-W + deep prefetch + kc rotation)
    admm_fused6<<<256, 256, 0, stream>>>(Whg, Wlg, DAh, DAl, outp);
}